// Round 8
// baseline (21903.539 us; speedup 1.0000x reference)
//
#include <hip/hip_runtime.h>

#define B_ 4096
#define L_ 15
#define NSTEP_ 5
#define VOC_ 30005
#define PAD_ 30003

typedef _Float16 f16;
typedef f16  f16x8 __attribute__((ext_vector_type(8)));
typedef float f32x16 __attribute__((ext_vector_type(16)));

__device__ __forceinline__ float sigf(float x){ return 1.0f/(1.0f+expf(-x)); }

#define MFMA_(d,a,b) d = __builtin_amdgcn_mfma_f32_32x32x16_f16(a,b,d,0,0,0)

__device__ __forceinline__ void gll16(const f16* g, f16* l){
  __builtin_amdgcn_global_load_lds(
      (const __attribute__((address_space(1))) void*)g,
      (__attribute__((address_space(3))) void*)l, 16, 0, 0);
}

// ---------------------------------------------------------------- params
struct RecParams {
  const f16 *A1h_0,*A1l_0,*A1h_1,*A1l_1;   // x-part arrays (layer1 path)
  const f16 *A2h_0,*A2l_0,*A2h_1,*A2l_1;   // h-part arrays
  const f16 *Wfh_0,*Wfl_0,*Wfh_1,*Wfl_1;   // fragment-order W
  const float *bias_0,*bias_1;
  const f16 *embH,*embL,*flagpg;           // split emb table + {1,0..|0..} page
  const int *st,*ids;
  float *c_0,*c_1,*h2_0,*h2_1;
  f16 *hh_0,*hl_0,*hh_1,*hl_1;
  int lda1, lda2, ldh, ldh2, k1p, k2p, first, gather, t_0, t_1, pos, b0c, act0, act1;
};

// swizzled byte offset into a [128 rows][16 k] f16 (4KB) LDS array (Gray).
__device__ __forceinline__ int swz(int row, int s){
  int u = ((row&7)<<1) | s;
  return ((row>>3)<<8) + ((u ^ (u>>1))<<4);
}

// --------------------------------- fused split-f16 MFMA GEMM + LSTM cell
// BK=32, A staged via global_load_lds into TRIPLE-buffered swizzled LDS
// (source pre-swizzled per Gray-decode), B fragments from global into regs
// (kt16 2ph half prefetched across the raw barrier), counted vmcnt only.
__global__ __launch_bounds__(256,2) void rec_gemm(RecParams p){
  const int bxe = blockIdx.x;
  const int ct4 = bxe & 15;          // column-tile group (0..15)
  const int dir = bxe >> 4;          // 0 = fw, 1 = bw
  if (!(dir ? p.act1 : p.act0)) return;
  const f16* A1h = dir ? p.A1h_1 : p.A1h_0;
  const f16* A1l = dir ? p.A1l_1 : p.A1l_0;
  const f16* A2h = dir ? p.A2h_1 : p.A2h_0;
  const f16* A2l = dir ? p.A2l_1 : p.A2l_0;
  const f16* Wfh = dir ? p.Wfh_1 : p.Wfh_0;
  const f16* Wfl = dir ? p.Wfl_1 : p.Wfl_0;
  const float* bias = dir ? p.bias_1 : p.bias_0;
  float* cbuf = dir ? p.c_1 : p.c_0;
  float* h2   = dir ? p.h2_1 : p.h2_0;
  f16* hhb = dir ? p.hh_1 : p.hh_0;
  f16* hlb = dir ? p.hl_1 : p.hl_0;
  const int tcur = dir ? p.t_1 : p.t_0;

  const int tid  = threadIdx.x;
  const int lane = tid & 63;
  const int w    = tid >> 6;
  const int mbase = blockIdx.y*128;

  __shared__ union {
    float z[128*128];          // 64 KB epilogue
    f16   stg[3][4][2048];     // 3 bufs x {Ah_s0,Al_s0,Ah_s1,Al_s1} x 4KB
  } sm;

  f32x16 accM[2][2], accX[2][2];
#pragma unroll
  for (int i=0;i<2;i++)
#pragma unroll
    for (int j=0;j<2;j++)
#pragma unroll
      for (int r=0;r<16;r++){ accM[i][j][r]=0.f; accX[i][j][r]=0.f; }

  // a-frag read offsets (validated scheme, per 4KB sub-array)
  const int arow = (w&1)*64 + (lane&31);
  const int fs = lane>>5;
  const int aoff0 = swz(arow,    fs), aoff1 = swz(arow+32, fs);

  // b-frag global fragment pointers
  const int ct0 = ct4*4 + (w>>1)*2;
  const f16* WfhL = Wfh + (size_t)lane*8;
  const f16* WflL = Wfl + (size_t)lane*8;

  // gll staging: thread tid writes LDS unit tid (linear); source (row,s) =
  // Gray-decode of unit within its 8-row group -> LDS content matches swz().
  int ug = tid & 15; ug ^= ug>>1; ug ^= ug>>2;
  const int rowS = ((tid>>4)<<3) + (ug>>1);
  const int sS   = ug & 1;
  const int ktot = p.k1p + p.k2p;

  // gather-mode hoisted tokens (per this thread's source row)
  int tokT=0, tokI=0, zflag=0;
  if (p.gather){
    int gb = p.b0c + mbase + rowS;
    tokT = p.st [gb*L_ + tcur];
    tokI = p.ids[gb*L_ + tcur];
    zflag = (tcur == p.pos) ? 1 : 0;
  }
  const f16* zeros = p.flagpg + 8;     // 16B of f16 zeros
  const f16* ones0 = p.flagpg;         // {1,0,0,0,0,0,0,0}

  auto stage = [&](int ph, int buf){
    f16* d0 = &sm.stg[buf][0][w<<9];
    f16* d1 = &sm.stg[buf][1][w<<9];
    f16* d2 = &sm.stg[buf][2][w<<9];
    f16* d3 = &sm.stg[buf][3][w<<9];
    if (ph < p.k1p){
      if (p.gather){
        if (ph < 8){
          if (zflag){ gll16(zeros,d0); gll16(zeros,d1); gll16(zeros,d2); gll16(zeros,d3); }
          else {
            size_t base = (size_t)tokT*256 + ph*32 + sS*8;
            gll16(p.embH+base, d0); gll16(p.embL+base, d1);
            gll16(p.embH+base+16, d2); gll16(p.embL+base+16, d3);
          }
        } else if (ph < 16){
          size_t base = (size_t)tokI*256 + (ph-8)*32 + sS*8;
          gll16(p.embH+base, d0); gll16(p.embL+base, d1);
          gll16(p.embH+base+16, d2); gll16(p.embL+base+16, d3);
        } else {  // ph==16: posflag at k=512 (sub0, sS==0, j==0), rest 0
          const f16* s0 = (sS==0 && zflag) ? ones0 : zeros;
          gll16(s0,d0); gll16(zeros,d1); gll16(zeros,d2); gll16(zeros,d3);
        }
      } else {
        long base = (long)(mbase+rowS)*p.lda1 + ph*32 + sS*8;
        gll16(A1h+base, d0); gll16(A1l+base, d1);
        gll16(A1h+base+16, d2); gll16(A1l+base+16, d3);
      }
    } else {
      long base = (long)(mbase+rowS)*p.lda2 + (ph - p.k1p)*32 + sS*8;
      gll16(A2h+base, d0); gll16(A2l+base, d1);
      gll16(A2h+base+16, d2); gll16(A2l+base+16, d3);
    }
  };
  auto loadB = [&](int kt16, f16x8* r){
    size_t base = ((size_t)kt16*64 + ct0)*512;
    r[0] = *(const f16x8*)(WfhL + base);
    r[1] = *(const f16x8*)(WfhL + base + 512);
    r[2] = *(const f16x8*)(WflL + base);
    r[3] = *(const f16x8*)(WflL + base + 512);
  };

  f16x8 rb0[4], rb1[4];
  // prologue: stage ph0,ph1; preload B(kt16=0); publish buf0
  stage(0,0); stage(1,1);
  loadB(0, rb0);
  asm volatile("s_waitcnt vmcnt(8)" ::: "memory");   // drain stage(0) only
  __builtin_amdgcn_s_barrier();
  __builtin_amdgcn_sched_barrier(0);

  int bR = 0;
  for (int ph=0; ph<ktot; ++ph){
    const char* s0h = (const char*)sm.stg[bR][0];
    const char* s0l = (const char*)sm.stg[bR][1];
    const char* s1h = (const char*)sm.stg[bR][2];
    const char* s1l = (const char*)sm.stg[bR][3];
    f16x8 a00h = *(const f16x8*)(s0h + aoff0);
    f16x8 a01h = *(const f16x8*)(s0h + aoff1);
    f16x8 a00l = *(const f16x8*)(s0l + aoff0);
    f16x8 a01l = *(const f16x8*)(s0l + aoff1);
    f16x8 a10h = *(const f16x8*)(s1h + aoff0);
    f16x8 a11h = *(const f16x8*)(s1h + aoff1);
    f16x8 a10l = *(const f16x8*)(s1l + aoff0);
    f16x8 a11l = *(const f16x8*)(s1l + aoff1);
    // issue in-phase B half, then A-stage two ahead (stays in flight 2 phases)
    loadB(2*ph+1, rb1);
    if (ph+2 < ktot) stage(ph+2, (bR+2>=3)?(bR-1):(bR+2));
    __builtin_amdgcn_s_setprio(1);
    // sub0 (kt16=2ph) — compiler waits counted vmcnt for rb0 + lgkm for a
    MFMA_(accM[0][0], a00h, rb0[0]); MFMA_(accX[0][0], a00h, rb0[2]); MFMA_(accX[0][0], a00l, rb0[0]);
    MFMA_(accM[1][0], a01h, rb0[0]); MFMA_(accX[1][0], a01h, rb0[2]); MFMA_(accX[1][0], a01l, rb0[0]);
    MFMA_(accM[0][1], a00h, rb0[1]); MFMA_(accX[0][1], a00h, rb0[3]); MFMA_(accX[0][1], a00l, rb0[1]);
    MFMA_(accM[1][1], a01h, rb0[1]); MFMA_(accX[1][1], a01h, rb0[3]); MFMA_(accX[1][1], a01l, rb0[1]);
    // sub1 (kt16=2ph+1)
    MFMA_(accM[0][0], a10h, rb1[0]); MFMA_(accX[0][0], a10h, rb1[2]); MFMA_(accX[0][0], a10l, rb1[0]);
    MFMA_(accM[1][0], a11h, rb1[0]); MFMA_(accX[1][0], a11h, rb1[2]); MFMA_(accX[1][0], a11l, rb1[0]);
    MFMA_(accM[0][1], a10h, rb1[1]); MFMA_(accX[0][1], a10h, rb1[3]); MFMA_(accX[0][1], a10l, rb1[1]);
    MFMA_(accM[1][1], a11h, rb1[1]); MFMA_(accX[1][1], a11h, rb1[3]); MFMA_(accX[1][1], a11l, rb1[1]);
    __builtin_amdgcn_s_setprio(0);
    // prefetch next phase's first B half (crosses the barrier, 16 VGPR)
    if (ph+1 < ktot) loadB(2*ph+2, rb0);
    // publish: newest 8 ops are {stage(ph+2)4, rb0-next4}; vmcnt(8) drains
    // everything older incl. stage(ph+1) -> safe to read next phase.
    asm volatile("s_waitcnt vmcnt(8) lgkmcnt(0)" ::: "memory");
    __builtin_amdgcn_s_barrier();
    __builtin_amdgcn_sched_barrier(0);
    bR = (bR+1==3)?0:(bR+1);
  }

  __syncthreads();   // full drain once before reusing union as z

  // ---- epilogue: z tiles -> LDS (regroup gates), then fused LSTM cell
#pragma unroll
  for (int tm=0;tm<2;tm++)
#pragma unroll
   for (int tn=0;tn<2;tn++){
    int lcol = (w>>1)*64 + tn*32 + (lane&31);
    float bv = bias[ct4*128 + lcol];
#pragma unroll
    for (int r=0;r<16;r++){
      int lrow = (w&1)*64 + tm*32 + (r&3) + 8*(r>>2) + 4*(lane>>5);
      sm.z[lrow*128 + lcol] = accM[tm][tn][r] + 0.000244140625f*accX[tm][tn][r] + bv;
    }
   }
  __syncthreads();

  const int nb = ct4*32;   // hidden-unit base for this block
#pragma unroll
  for (int it=0; it<16; ++it){
    int idx = it*256 + tid;
    int nq = idx & 31, row = idx >> 5;
    float4 g4 = *(const float4*)&sm.z[row*128 + nq*4];
    int m = mbase + row, n = nb + nq;
    float cp = p.first ? 0.f : cbuf[(size_t)m*512 + n];
    float cc = sigf(g4.y)*cp + sigf(g4.x)*tanhf(g4.z);
    float hv = sigf(g4.w)*tanhf(cc);
    cbuf[(size_t)m*512 + n] = cc;
    f16 hi = (f16)hv;
    f16 lo = (f16)((hv - (float)hi)*4096.0f);
    hhb[(size_t)m*p.ldh + n] = hi;
    hlb[(size_t)m*p.ldh + n] = lo;
    if (h2) h2[(size_t)m*p.ldh2 + n] = hv;
  }
}

// ------------------------------------------- prep: W in MFMA fragment order
__global__ void prep_w0(const float* Wih, const float* Whh, const float* b0,
                        f16* Wfh, f16* Wfl, float* bp){
  int gid = blockIdx.x*blockDim.x + threadIdx.x;
  const int PER_DIR = 66*64*64*8;
  if (gid >= 2*PER_DIR) return;
  int dir = gid / PER_DIR;
  int rem = gid % PER_DIR;
  int j = rem & 7, lane = (rem>>3)&63, ct = (rem>>9)&63, kt16 = rem>>15;
  int n4g = ct*32 + (lane&31);
  int n = n4g>>2, g = n4g&3;
  int srow = dir*2048 + g*512 + n;
  int k = kt16*16 + ((lane>>5)<<3) + j;     // padded K: [Wih 513 | pad 31 | Whh 512]
  float v;
  if (k < 513)       v = Wih[(size_t)srow*513 + k];
  else if (k < 544)  v = 0.f;
  else               v = Whh[(size_t)srow*512 + (k-544)];
  f16 hi = (f16)v;
  Wfh[gid] = hi;
  Wfl[gid] = (f16)((v - (float)hi)*4096.0f);
  if (kt16==0 && (lane>>5)==0 && j==0) bp[dir*2048 + n4g] = b0[srow];
}

__global__ void prep_w1(const float* Wih, const float* Whh, const float* b1,
                        f16* Wfh, f16* Wfl, float* bp){
  int gid = blockIdx.x*blockDim.x + threadIdx.x;
  const int PER_DIR = 96*64*64*8;
  if (gid >= 2*PER_DIR) return;
  int dir = gid / PER_DIR;
  int rem = gid % PER_DIR;
  int j = rem & 7, lane = (rem>>3)&63, ct = (rem>>9)&63, kt16 = rem>>15;
  int n4g = ct*32 + (lane&31);
  int n = n4g>>2, g = n4g&3;
  int srow = dir*2048 + g*512 + n;
  int k = kt16*16 + ((lane>>5)<<3) + j;     // [Wih 1024 | Whh 512]
  float v;
  if (k < 1024) v = Wih[(size_t)srow*1024 + k];
  else          v = Whh[(size_t)srow*512 + (k-1024)];
  f16 hi = (f16)v;
  Wfh[gid] = hi;
  Wfl[gid] = (f16)((v - (float)hi)*4096.0f);
  if (kt16==0 && (lane>>5)==0 && j==0) bp[dir*2048 + n4g] = b1[srow];
}

__global__ void prep_emb(const float* emb, f16* eh, f16* el){
  int gid = blockIdx.x*blockDim.x + threadIdx.x;
  if (gid >= VOC_*256) return;
  float v = emb[gid];
  f16 hi = (f16)v;
  eh[gid] = hi;
  el[gid] = (f16)((v - (float)hi)*4096.0f);
}

__global__ void prep_mlpwt(const float* mW, float* wt){
  int gid = blockIdx.x*blockDim.x + threadIdx.x;
  if (gid >= 100*1040) return;
  int j = gid / 1040, k = gid % 1040;
  wt[k*100 + j] = mW[gid];
}

__global__ __launch_bounds__(128) void prep_encproj(const float* enc, const float* delv,
                        const float* holdv, const float* m1W, const float* m1b, float* ep){
  int r = blockIdx.x;
  __shared__ float row[256];
  const float* src = (r < VOC_) ? enc + (size_t)r*256 : (r == VOC_ ? delv : holdv);
  for (int i=threadIdx.x;i<256;i+=128) row[i]=src[i];
  __syncthreads();
  int j = threadIdx.x;
  if (j < 100){
    double s = (double)m1b[j];
    const float* wr = m1W + (size_t)j*298;
    for (int k=0;k<256;k++) s += (double)wr[k] * (double)row[k];
    ep[(size_t)r*100 + j] = (float)s;
  }
}

__global__ void init_st(const int* ids, const int* seqlen, int* st, int* len, f16* flagpg){
  int gid = blockIdx.x*blockDim.x + threadIdx.x;
  if (gid < B_*L_) st[gid] = ids[gid];
  if (gid < B_)    len[gid] = seqlen[gid];
  if (gid < 16)    flagpg[gid] = (gid==0) ? (f16)1.0f : (f16)0.0f;
}

__global__ void sentinel(float* out, float v){
  int gid = blockIdx.x*blockDim.x + threadIdx.x;
  if (gid < B_*NSTEP_) out[gid] = v;
}

// ------------------------------------------------- scoring + sequence edit
__global__ __launch_bounds__(128) void score_update(
    const float* pooled, const float* keypos, const float* mWt, const float* mb,
    const float* ep, const float* m1W, const int* repw, const int* valid,
    int* st, int* len, float* outPis, float* outActs, int step, int pos, int b0){
  int b = blockIdx.x;
  int bg = b0 + b;
  __shared__ float rep[1040];
  __shared__ float r100[100];
  __shared__ double sc[42];
  int tid = threadIdx.x;
  for (int i=tid;i<1024;i+=128) rep[i] = pooled[(size_t)b*1024+i];
  if (tid < 16){
    if (tid == 0) rep[1024] = keypos[bg*L_+pos];
    else          rep[1024+tid] = ((tid-1)==pos) ? 1.f : 0.f;
  }
  __syncthreads();
  if (tid < 100){
    double s = (double)mb[tid];
    for (int k=0;k<1040;k++) s += (double)mWt[k*100+tid] * (double)rep[k];
    r100[tid] = (float)s;
  }
  __syncthreads();
  if (tid < 42){
    int row = (tid < 40) ? repw[((size_t)bg*NSTEP_+step)*40 + tid] : (VOC_ + (tid-40));
    const float* er = ep + (size_t)row*100;
    double s = 0.0;
    for (int j=0;j<100;j++) s += (double)er[j] * (double)r100[j];
    for (int j=0;j<100;j++) s += (double)m1W[j*298 + 256 + tid] * (double)r100[j];
    sc[tid] = s;
  }
  __syncthreads();
  if (tid == 0){
    double mx = sc[0]; int am = 0;
    for (int k=1;k<42;k++) if (sc[k] > mx){ mx = sc[k]; am = k; }
    double sum = 0.0;
    for (int k=0;k<42;k++) sum += exp(sc[k]-mx);
    float pi = (float)(1.0/sum);
    int vid = valid[bg*NSTEP_+step];
    int ln  = len[bg];
    int repb = (am < 20) ? 1 : 0;
    int insb = (am >= 20 && am < 40) ? 1 : 0;
    int delb = (am == 40) ? 1 : 0;
    int repf = repb*vid;
    int insf = insb*vid*(((ln+insb) <= 15) ? 1 : 0);
    int delf = delb*vid*(((ln-delb) >  2) ? 1 : 0);
    int T = L_ - pos;
    int tail[13];
    for (int j=0;j<T;j++) tail[j] = st[bg*L_+pos+j];
    int aw = repw[((size_t)bg*NSTEP_+step)*40 + (am < 20 ? am : 19)];
    for (int j=0;j<T;j++){
      int rv = (j==0) ? aw : tail[j];
      int iv = (j==0) ? aw : tail[j-1];
      int dv = (j < T-1) ? tail[j+1] : PAD_;
      int hv = tail[j];
      int nv = repf ? rv : (insf ? iv : (delf ? dv : hv));
      st[bg*L_+pos+j] = nv;
    }
    len[bg] = ln + insf - delf;
    outPis[bg*NSTEP_+step]  = pi;
    outActs[bg*NSTEP_+step] = (float)am;
  }
}

__global__ void finalize(const int* st, const int* len, float* out){
  int gid = blockIdx.x*blockDim.x + threadIdx.x;
  if (gid < B_*L_)            out[2*B_*NSTEP_ + gid] = (float)st[gid];
  else if (gid < B_*L_ + B_)  out[2*B_*NSTEP_ + B_*L_ + (gid - B_*L_)] = (float)len[gid - B_*L_];
}

// ---------------------------------------------------------------- launch
extern "C" void kernel_launch(void* const* d_in, const int* in_sizes, int n_in,
                              void* d_out, int out_size, void* d_ws, size_t ws_size,
                              hipStream_t stream) {
  const int*   ids    = (const int*)  d_in[0];
  const float* keypos = (const float*)d_in[1];
  const int*   seqlen = (const int*)  d_in[2];
  const int*   repw   = (const int*)  d_in[3];
  const int*   valid  = (const int*)  d_in[4];
  const float* emb    = (const float*)d_in[5];
  const float* enc    = (const float*)d_in[6];
  const float* Wih0   = (const float*)d_in[7];
  const float* Whh0   = (const float*)d_in[8];
  const float* b0     = (const float*)d_in[9];
  const float* Wih1   = (const float*)d_in[10];
  const float* Whh1   = (const float*)d_in[11];
  const float* b1     = (const float*)d_in[12];
  const float* delv   = (const float*)d_in[13];
  const float* holdv  = (const float*)d_in[14];
  const float* mW     = (const float*)d_in[15];
  const float* mb     = (const float*)d_in[16];
  const float* m1W    = (const float*)d_in[17];
  const float* m1b    = (const float*)d_in[18];
  float* out = (float*)d_out;

  const size_t W0PD = (size_t)66*64*64*8;   // f16 per dir
  const size_t W1PD = (size_t)96*64*64*8;

  char* ws = (char*)d_ws;
  size_t off = 0;
  auto allocB = [&](size_t bytes) -> char* {
    char* pp = ws + off; off += (bytes + 255) & ~size_t(255); return pp;
  };
  f16*  Wf0h = (f16*)allocB(2*W0PD*2);
  f16*  Wf0l = (f16*)allocB(2*W0PD*2);
  f16*  Wf1h = (f16*)allocB(2*W1PD*2);
  f16*  Wf1l = (f16*)allocB(2*W1PD*2);
  float* bp0 = (float*)allocB(4096*4);
  float* bp1 = (float*)allocB(4096*4);
  f16*  embH = (f16*)allocB((size_t)VOC_*256*2);
  f16*  embL = (f16*)allocB((size_t)VOC_*256*2);
  float* mWt = (float*)allocB(104000*4);
  float* ep  = (float*)allocB((size_t)30007*100*4);
  int* stbuf  = (int*)allocB(B_*L_*4);
  int* lenbuf = (int*)allocB(B_*4);
  f16* flagpg = (f16*)allocB(256);
  size_t fixedB = off;

  const int cands[6] = {4096, 2048, 1024, 512, 256, 128};
  int Bc = 0;
  for (int ci=0; ci<6; ++ci){
    size_t c = cands[ci];
    size_t chunkB = c*(size_t)(15*1024*2*2 + 4*512*2*2 + 2*512*4 + 2*512*4 + 1024*4) + 8*256;
    if (fixedB + chunkB <= ws_size){ Bc = (int)c; break; }
  }
  if (!Bc){
    float code = 100000.0f + (float)(ws_size >> 20);
    sentinel<<<(B_*NSTEP_+255)/256,256,0,stream>>>(out, code);
    return;
  }
  f16* o0h = (f16*)allocB((size_t)L_*Bc*1024*2);
  f16* o0l = (f16*)allocB((size_t)L_*Bc*1024*2);
  f16* h1h = (f16*)allocB((size_t)4*Bc*512*2);
  f16* h1l = (f16*)allocB((size_t)4*Bc*512*2);
  float* c0 = (float*)allocB((size_t)2*Bc*512*4);
  float* c1 = (float*)allocB((size_t)2*Bc*512*4);
  float* pooled = (float*)allocB((size_t)Bc*1024*4);

  prep_w0<<<(int)((2*W0PD+255)/256),256,0,stream>>>(Wih0, Whh0, b0, Wf0h, Wf0l, bp0);
  prep_w1<<<(int)((2*W1PD+255)/256),256,0,stream>>>(Wih1, Whh1, b1, Wf1h, Wf1l, bp1);
  prep_emb<<<(VOC_*256+255)/256,256,0,stream>>>(emb, embH, embL);
  prep_mlpwt<<<(100*1040+255)/256,256,0,stream>>>(mW, mWt);
  prep_encproj<<<30007,128,0,stream>>>(enc, delv, holdv, m1W, m1b, ep);
  init_st<<<(B_*L_+255)/256,256,0,stream>>>(ids, seqlen, stbuf, lenbuf, flagpg);

  for (int b0c=0; b0c<B_; b0c+=Bc){
    for (int step=0; step<NSTEP_; ++step){
      int pos = step + 2;   // i % 12 + 2 for i=0..4

      for (int ts=0; ts<L_; ++ts){
        int tf = ts, tb = 14-ts;
        RecParams p{};
        p.gather = 1; p.t_0 = tf; p.t_1 = tb; p.pos = pos; p.b0c = b0c;
        p.embH = embH; p.embL = embL; p.flagpg = flagpg; p.st = stbuf; p.ids = ids;
        p.k1p = 17; p.k2p = ts ? 16 : 0;
        size_t of0 = (size_t)(ts?tf-1:0)*Bc*1024;
        size_t of1 = (size_t)(ts?tb+1:0)*Bc*1024 + (ts?512:0);
        p.A2h_0 = o0h + of0;  p.A2l_0 = o0l + of0;
        p.A2h_1 = o0h + of1;  p.A2l_1 = o0l + of1;
        p.lda2 = 1024;
        p.Wfh_0 = Wf0h;        p.Wfl_0 = Wf0l;
        p.Wfh_1 = Wf0h + W0PD; p.Wfl_1 = Wf0l + W0PD;
        p.bias_0 = bp0; p.bias_1 = bp0 + 2048;
        p.c_0 = c0; p.c_1 = c0 + (size_t)Bc*512;
        p.hh_0 = o0h + (size_t)tf*Bc*1024;       p.hl_0 = o0l + (size_t)tf*Bc*1024;
        p.hh_1 = o0h + (size_t)tb*Bc*1024 + 512; p.hl_1 = o0l + (size_t)tb*Bc*1024 + 512;
        p.ldh = 1024;
        p.h2_0 = nullptr; p.h2_1 = nullptr; p.ldh2 = 1024;
        p.first = (ts==0); p.act0 = 1; p.act1 = 1;
        rec_gemm<<<dim3(32,Bc/128),256,0,stream>>>(p);
      }

      int nL1 = L_ - pos;
      for (int ts=0; ts<nL1; ++ts){
        RecParams p{};
        int tf = ts, tb = 14-ts;
        int parR = (ts-1)&1, parW = ts&1;
        p.gather = 0; p.flagpg = flagpg;
        p.A1h_0 = o0h + (size_t)tf*Bc*1024;  p.A1l_0 = o0l + (size_t)tf*Bc*1024;
        p.A1h_1 = o0h + (size_t)tb*Bc*1024;  p.A1l_1 = o0l + (size_t)tb*Bc*1024;
        p.lda1 = 1024; p.k1p = 32;
        p.k2p  = ts ? 16 : 0;
        size_t r0 = (size_t)(0*2 + (ts?parR:0))*Bc*512;
        size_t r1 = (size_t)(1*2 + (ts?parR:0))*Bc*512;
        p.A2h_0 = h1h + r0; p.A2l_0 = h1l + r0;
        p.A2h_1 = h1h + r1; p.A2l_1 = h1l + r1;
        p.lda2 = 512;
        p.Wfh_0 = Wf1h;        p.Wfl_0 = Wf1l;
        p.Wfh_1 = Wf1h + W1PD; p.Wfl_1 = Wf1l + W1PD;
        p.bias_0 = bp1; p.bias_1 = bp1 + 2048;
        p.c_0 = c1; p.c_1 = c1 + (size_t)Bc*512;
        size_t w0 = (size_t)(0*2 + parW)*Bc*512;
        size_t w1 = (size_t)(1*2 + parW)*Bc*512;
        p.hh_0 = h1h + w0; p.hl_0 = h1l + w0;
        p.hh_1 = h1h + w1; p.hl_1 = h1l + w1;
        p.ldh = 512;
        p.h2_0 = (ts == pos)    ? pooled        : nullptr;
        p.h2_1 = (ts == 14-pos) ? (pooled+512)  : nullptr;
        p.ldh2 = 1024;
        p.first = (ts==0);
        p.act0 = (ts <= pos) ? 1 : 0; p.act1 = 1;
        rec_gemm<<<dim3(32,Bc/128),256,0,stream>>>(p);
      }

      score_update<<<Bc,128,0,stream>>>(pooled, keypos, mWt, mb, ep, m1W, repw, valid,
                                        stbuf, lenbuf, out, out + B_*NSTEP_, step, pos, b0c);
    }
  }
  finalize<<<(B_*L_+B_+255)/256,256,0,stream>>>(stbuf, lenbuf, out);
}

// Round 9
// 20196.648 us; speedup vs baseline: 1.0845x; 1.0845x over previous
//
#include <hip/hip_runtime.h>

#define B_ 4096
#define L_ 15
#define NSTEP_ 5
#define VOC_ 30005
#define PAD_ 30003

typedef _Float16 f16;
typedef f16  f16x8 __attribute__((ext_vector_type(8)));
typedef float f32x16 __attribute__((ext_vector_type(16)));

__device__ __forceinline__ float sigf(float x){ return 1.0f/(1.0f+expf(-x)); }

#define MFMA_(d,a,b) d = __builtin_amdgcn_mfma_f32_32x32x16_f16(a,b,d,0,0,0)

// ---------------------------------------------------------------- params
struct RecParams {
  const f16 *A1h_0,*A1l_0,*A1h_1,*A1l_1;   // x-part arrays (layer1 path)
  const f16 *A2h_0,*A2l_0,*A2h_1,*A2l_1;   // h-part arrays
  const f16 *Wfh_0,*Wfl_0,*Wfh_1,*Wfl_1;   // fragment-order W
  const float *bias_0,*bias_1;
  const f16 *embH,*embL;                   // split emb table (gather mode)
  const int *st,*ids;
  float *c_0,*c_1,*h2_0,*h2_1;
  f16 *hh_0,*hl_0,*hh_1,*hl_1;
  int lda1, lda2, ldh, ldh2, k1p, k2p, first, gather, t_0, t_1, pos, b0c, act0, act1;
};

// swizzled byte offset into a [128 rows][16 k] f16 (4KB) LDS array (Gray).
__device__ __forceinline__ int swz(int row, int s){
  int u = ((row&7)<<1) | s;
  return ((row>>3)<<8) + ((u ^ (u>>1))<<4);
}

// --------------------------------- fused split-f16 MFMA GEMM + LSTM cell
// C(Bc x 2048) = A(Bc x K) @ W^T (+bias); A,W as (hi, lo*2^12) f16 pairs.
// 3 MFMA passes: accM += Ah*Wh; accX += Ah*Wl + Al*Wh; z = accM + 2^-12*accX.
// BK=32. B-fragments load DIRECTLY from global (fragment-linear Wf layout).
// 1-D grid, id -> (ct4 = id&15, dir = (id>>4)&1, rt = id>>5): all readers of
// a given W-slice are ids == ctdir (mod 32) -> ONE XCD (32 % 8 == 0), so the
// per-XCD W working set is ~2-3 MB and W stays L2-resident across dispatches.
__global__ __launch_bounds__(256,2) void rec_gemm(RecParams p){
  const int id  = blockIdx.x;
  const int ct4 = id & 15;           // column-tile group (0..15)
  const int dir = (id >> 4) & 1;     // 0 = fw, 1 = bw
  if (!(dir ? p.act1 : p.act0)) return;
  const f16* A1h = dir ? p.A1h_1 : p.A1h_0;
  const f16* A1l = dir ? p.A1l_1 : p.A1l_0;
  const f16* A2h = dir ? p.A2h_1 : p.A2h_0;
  const f16* A2l = dir ? p.A2l_1 : p.A2l_0;
  const f16* Wfh = dir ? p.Wfh_1 : p.Wfh_0;
  const f16* Wfl = dir ? p.Wfl_1 : p.Wfl_0;
  const float* bias = dir ? p.bias_1 : p.bias_0;
  float* cbuf = dir ? p.c_1 : p.c_0;
  float* h2   = dir ? p.h2_1 : p.h2_0;
  f16* hhb = dir ? p.hh_1 : p.hh_0;
  f16* hlb = dir ? p.hl_1 : p.hl_0;
  const int tcur = dir ? p.t_1 : p.t_0;

  const int tid  = threadIdx.x;
  const int lane = tid & 63;
  const int w    = tid >> 6;
  const int mbase = (id >> 5) * 128;

  __shared__ union {
    float z[128*128];          // 64 KB epilogue
    f16   stg[8][2048];        // [buf*4 + {Ah_s0,Al_s0,Ah_s1,Al_s1}] 4KB each
  } sm;

  f32x16 accM[2][2], accX[2][2];
#pragma unroll
  for (int i=0;i<2;i++)
#pragma unroll
    for (int j=0;j<2;j++)
#pragma unroll
      for (int r=0;r<16;r++){ accM[i][j][r]=0.f; accX[i][j][r]=0.f; }

  // a-frag read offsets (validated scheme, per 4KB sub-array)
  const int arow = (w&1)*64 + (lane&31);
  const int fs = lane>>5;
  const int aoff0 = swz(arow,    fs), aoff1 = swz(arow+32, fs);

  // b-frag global fragment pointers
  const int ct0 = ct4*4 + (w>>1)*2;
  const f16* WfhL = Wfh + (size_t)lane*8;
  const f16* WflL = Wfl + (size_t)lane*8;

  // A staging: thread stages unit (srow, ss) for 4 arrays
  const int srow = tid >> 1, ss = tid & 1;
  const int sws = swz(srow, ss);
  const int ktot = p.k1p + p.k2p;

  // gather-mode hoisted tokens
  int tokT=0, tokI=0, zflag=0;
  if (p.gather){
    int gb = p.b0c + mbase + srow;
    tokT = p.st [gb*L_ + tcur];
    tokI = p.ids[gb*L_ + tcur];
    zflag = (tcur == p.pos) ? 1 : 0;
  }

  f16x8 ra_h0, ra_l0, ra_h1, ra_l1;
  const f16x8 zero8 = {0,0,0,0,0,0,0,0};

  auto gload = [&](int ph){
    if (ph >= ktot) return;
    if (ph < p.k1p){
      if (p.gather){
        if (ph < 8){                     // embt part (cols 0..255)
          if (zflag){ ra_h0=zero8; ra_l0=zero8; ra_h1=zero8; ra_l1=zero8; }
          else {
            size_t base = (size_t)tokT*256 + ph*32 + ss*8;
            ra_h0 = *(const f16x8*)(p.embH + base);
            ra_l0 = *(const f16x8*)(p.embL + base);
            ra_h1 = *(const f16x8*)(p.embH + base + 16);
            ra_l1 = *(const f16x8*)(p.embL + base + 16);
          }
        } else if (ph < 16){             // emb0 part (cols 256..511)
          size_t base = (size_t)tokI*256 + (ph-8)*32 + ss*8;
          ra_h0 = *(const f16x8*)(p.embH + base);
          ra_l0 = *(const f16x8*)(p.embL + base);
          ra_h1 = *(const f16x8*)(p.embH + base + 16);
          ra_l1 = *(const f16x8*)(p.embL + base + 16);
        } else {                         // ph==16: posflag @512, rest 0
          ra_h0 = zero8; ra_l0 = zero8; ra_h1 = zero8; ra_l1 = zero8;
          if (ss == 0) ra_h0[0] = zflag ? (f16)1.0f : (f16)0.0f;
        }
      } else {
        long base = (long)(mbase+srow)*p.lda1 + ph*32 + ss*8;
        ra_h0 = *(const f16x8*)(A1h + base);
        ra_l0 = *(const f16x8*)(A1l + base);
        ra_h1 = *(const f16x8*)(A1h + base + 16);
        ra_l1 = *(const f16x8*)(A1l + base + 16);
      }
    } else {
      long base = (long)(mbase+srow)*p.lda2 + (ph - p.k1p)*32 + ss*8;
      ra_h0 = *(const f16x8*)(A2h + base);
      ra_l0 = *(const f16x8*)(A2l + base);
      ra_h1 = *(const f16x8*)(A2h + base + 16);
      ra_l1 = *(const f16x8*)(A2l + base + 16);
    }
  };
  auto swrite = [&](int buf){
    *(f16x8*)((char*)sm.stg[buf*4+0] + sws) = ra_h0;
    *(f16x8*)((char*)sm.stg[buf*4+1] + sws) = ra_l0;
    *(f16x8*)((char*)sm.stg[buf*4+2] + sws) = ra_h1;
    *(f16x8*)((char*)sm.stg[buf*4+3] + sws) = ra_l1;
  };

  gload(0); swrite(0); gload(1);
  __syncthreads();

  for (int ph=0; ph<ktot; ++ph){
    const int cur = ph & 1;
    // B fragments for this phase (global -> L2-resident W)
    size_t base0 = ((size_t)(ph*2+0)*64 + ct0)*512;
    size_t base1 = ((size_t)(ph*2+1)*64 + ct0)*512;
    f16x8 rbh00 = *(const f16x8*)(WfhL + base0);
    f16x8 rbh01 = *(const f16x8*)(WfhL + base0 + 512);
    f16x8 rbl00 = *(const f16x8*)(WflL + base0);
    f16x8 rbl01 = *(const f16x8*)(WflL + base0 + 512);
    f16x8 rbh10 = *(const f16x8*)(WfhL + base1);
    f16x8 rbh11 = *(const f16x8*)(WfhL + base1 + 512);
    f16x8 rbl10 = *(const f16x8*)(WflL + base1);
    f16x8 rbl11 = *(const f16x8*)(WflL + base1 + 512);
    // A fragments from LDS
    const char* s0h = (const char*)sm.stg[cur*4+0];
    const char* s0l = (const char*)sm.stg[cur*4+1];
    const char* s1h = (const char*)sm.stg[cur*4+2];
    const char* s1l = (const char*)sm.stg[cur*4+3];
    f16x8 a00h = *(const f16x8*)(s0h + aoff0);
    f16x8 a01h = *(const f16x8*)(s0h + aoff1);
    f16x8 a00l = *(const f16x8*)(s0l + aoff0);
    f16x8 a01l = *(const f16x8*)(s0l + aoff1);
    f16x8 a10h = *(const f16x8*)(s1h + aoff0);
    f16x8 a11h = *(const f16x8*)(s1h + aoff1);
    f16x8 a10l = *(const f16x8*)(s1l + aoff0);
    f16x8 a11l = *(const f16x8*)(s1l + aoff1);
    // stage next A tile (values loaded last phase), issue A(ph+2)
    if (ph+1 < ktot){ swrite((ph+1)&1); gload(ph+2); }
    // sub0
    MFMA_(accM[0][0], a00h, rbh00); MFMA_(accX[0][0], a00h, rbl00); MFMA_(accX[0][0], a00l, rbh00);
    MFMA_(accM[1][0], a01h, rbh00); MFMA_(accX[1][0], a01h, rbl00); MFMA_(accX[1][0], a01l, rbh00);
    MFMA_(accM[0][1], a00h, rbh01); MFMA_(accX[0][1], a00h, rbl01); MFMA_(accX[0][1], a00l, rbh01);
    MFMA_(accM[1][1], a01h, rbh01); MFMA_(accX[1][1], a01h, rbl01); MFMA_(accX[1][1], a01l, rbh01);
    // sub1
    MFMA_(accM[0][0], a10h, rbh10); MFMA_(accX[0][0], a10h, rbl10); MFMA_(accX[0][0], a10l, rbh10);
    MFMA_(accM[1][0], a11h, rbh10); MFMA_(accX[1][0], a11h, rbl10); MFMA_(accX[1][0], a11l, rbh10);
    MFMA_(accM[0][1], a10h, rbh11); MFMA_(accX[0][1], a10h, rbl11); MFMA_(accX[0][1], a10l, rbh11);
    MFMA_(accM[1][1], a11h, rbh11); MFMA_(accX[1][1], a11h, rbl11); MFMA_(accX[1][1], a11l, rbh11);
    __syncthreads();
  }

  // ---- epilogue: z tiles -> LDS (regroup gates), then fused LSTM cell
#pragma unroll
  for (int tm=0;tm<2;tm++)
#pragma unroll
   for (int tn=0;tn<2;tn++){
    int lcol = (w>>1)*64 + tn*32 + (lane&31);
    float bv = bias[ct4*128 + lcol];
#pragma unroll
    for (int r=0;r<16;r++){
      int lrow = (w&1)*64 + tm*32 + (r&3) + 8*(r>>2) + 4*(lane>>5);
      sm.z[lrow*128 + lcol] = accM[tm][tn][r] + 0.000244140625f*accX[tm][tn][r] + bv;
    }
   }
  __syncthreads();

  const int nb = ct4*32;   // hidden-unit base for this block
#pragma unroll
  for (int it=0; it<16; ++it){
    int idx = it*256 + tid;
    int nq = idx & 31, row = idx >> 5;
    float4 g4 = *(const float4*)&sm.z[row*128 + nq*4];
    int m = mbase + row, n = nb + nq;
    float cp = p.first ? 0.f : cbuf[(size_t)m*512 + n];
    float cc = sigf(g4.y)*cp + sigf(g4.x)*tanhf(g4.z);
    float hv = sigf(g4.w)*tanhf(cc);
    cbuf[(size_t)m*512 + n] = cc;
    f16 hi = (f16)hv;
    f16 lo = (f16)((hv - (float)hi)*4096.0f);
    hhb[(size_t)m*p.ldh + n] = hi;
    hlb[(size_t)m*p.ldh + n] = lo;
    if (h2) h2[(size_t)m*p.ldh2 + n] = hv;
  }
}

// ------------------------------------------- prep: W in MFMA fragment order
__global__ void prep_w0(const float* Wih, const float* Whh, const float* b0,
                        f16* Wfh, f16* Wfl, float* bp){
  int gid = blockIdx.x*blockDim.x + threadIdx.x;
  const int PER_DIR = 66*64*64*8;
  if (gid >= 2*PER_DIR) return;
  int dir = gid / PER_DIR;
  int rem = gid % PER_DIR;
  int j = rem & 7, lane = (rem>>3)&63, ct = (rem>>9)&63, kt16 = rem>>15;
  int n4g = ct*32 + (lane&31);
  int n = n4g>>2, g = n4g&3;
  int srow = dir*2048 + g*512 + n;
  int k = kt16*16 + ((lane>>5)<<3) + j;     // padded K: [Wih 513 | pad 31 | Whh 512]
  float v;
  if (k < 513)       v = Wih[(size_t)srow*513 + k];
  else if (k < 544)  v = 0.f;
  else               v = Whh[(size_t)srow*512 + (k-544)];
  f16 hi = (f16)v;
  Wfh[gid] = hi;
  Wfl[gid] = (f16)((v - (float)hi)*4096.0f);
  if (kt16==0 && (lane>>5)==0 && j==0) bp[dir*2048 + n4g] = b0[srow];
}

__global__ void prep_w1(const float* Wih, const float* Whh, const float* b1,
                        f16* Wfh, f16* Wfl, float* bp){
  int gid = blockIdx.x*blockDim.x + threadIdx.x;
  const int PER_DIR = 96*64*64*8;
  if (gid >= 2*PER_DIR) return;
  int dir = gid / PER_DIR;
  int rem = gid % PER_DIR;
  int j = rem & 7, lane = (rem>>3)&63, ct = (rem>>9)&63, kt16 = rem>>15;
  int n4g = ct*32 + (lane&31);
  int n = n4g>>2, g = n4g&3;
  int srow = dir*2048 + g*512 + n;
  int k = kt16*16 + ((lane>>5)<<3) + j;     // [Wih 1024 | Whh 512]
  float v;
  if (k < 1024) v = Wih[(size_t)srow*1024 + k];
  else          v = Whh[(size_t)srow*512 + (k-1024)];
  f16 hi = (f16)v;
  Wfh[gid] = hi;
  Wfl[gid] = (f16)((v - (float)hi)*4096.0f);
  if (kt16==0 && (lane>>5)==0 && j==0) bp[dir*2048 + n4g] = b1[srow];
}

__global__ void prep_emb(const float* emb, f16* eh, f16* el){
  int gid = blockIdx.x*blockDim.x + threadIdx.x;
  if (gid >= VOC_*256) return;
  float v = emb[gid];
  f16 hi = (f16)v;
  eh[gid] = hi;
  el[gid] = (f16)((v - (float)hi)*4096.0f);
}

__global__ void prep_mlpwt(const float* mW, float* wt){
  int gid = blockIdx.x*blockDim.x + threadIdx.x;
  if (gid >= 100*1040) return;
  int j = gid / 1040, k = gid % 1040;
  wt[k*100 + j] = mW[gid];
}

__global__ __launch_bounds__(128) void prep_encproj(const float* enc, const float* delv,
                        const float* holdv, const float* m1W, const float* m1b, float* ep){
  int r = blockIdx.x;
  __shared__ float row[256];
  const float* src = (r < VOC_) ? enc + (size_t)r*256 : (r == VOC_ ? delv : holdv);
  for (int i=threadIdx.x;i<256;i+=128) row[i]=src[i];
  __syncthreads();
  int j = threadIdx.x;
  if (j < 100){
    double s = (double)m1b[j];
    const float* wr = m1W + (size_t)j*298;
    for (int k=0;k<256;k++) s += (double)wr[k] * (double)row[k];
    ep[(size_t)r*100 + j] = (float)s;
  }
}

__global__ void init_st(const int* ids, const int* seqlen, int* st, int* len){
  int gid = blockIdx.x*blockDim.x + threadIdx.x;
  if (gid < B_*L_) st[gid] = ids[gid];
  if (gid < B_)    len[gid] = seqlen[gid];
}

__global__ void sentinel(float* out, float v){
  int gid = blockIdx.x*blockDim.x + threadIdx.x;
  if (gid < B_*NSTEP_) out[gid] = v;
}

// ------------------------------------------------- scoring + sequence edit
__global__ __launch_bounds__(128) void score_update(
    const float* pooled, const float* keypos, const float* mWt, const float* mb,
    const float* ep, const float* m1W, const int* repw, const int* valid,
    int* st, int* len, float* outPis, float* outActs, int step, int pos, int b0){
  int b = blockIdx.x;
  int bg = b0 + b;
  __shared__ float rep[1040];
  __shared__ float r100[100];
  __shared__ double sc[42];
  int tid = threadIdx.x;
  for (int i=tid;i<1024;i+=128) rep[i] = pooled[(size_t)b*1024+i];
  if (tid < 16){
    if (tid == 0) rep[1024] = keypos[bg*L_+pos];
    else          rep[1024+tid] = ((tid-1)==pos) ? 1.f : 0.f;
  }
  __syncthreads();
  if (tid < 100){
    double s = (double)mb[tid];
    for (int k=0;k<1040;k++) s += (double)mWt[k*100+tid] * (double)rep[k];
    r100[tid] = (float)s;
  }
  __syncthreads();
  if (tid < 42){
    int row = (tid < 40) ? repw[((size_t)bg*NSTEP_+step)*40 + tid] : (VOC_ + (tid-40));
    const float* er = ep + (size_t)row*100;
    double s = 0.0;
    for (int j=0;j<100;j++) s += (double)er[j] * (double)r100[j];
    for (int j=0;j<100;j++) s += (double)m1W[j*298 + 256 + tid] * (double)r100[j];
    sc[tid] = s;
  }
  __syncthreads();
  if (tid == 0){
    double mx = sc[0]; int am = 0;
    for (int k=1;k<42;k++) if (sc[k] > mx){ mx = sc[k]; am = k; }
    double sum = 0.0;
    for (int k=0;k<42;k++) sum += exp(sc[k]-mx);
    float pi = (float)(1.0/sum);
    int vid = valid[bg*NSTEP_+step];
    int ln  = len[bg];
    int repb = (am < 20) ? 1 : 0;
    int insb = (am >= 20 && am < 40) ? 1 : 0;
    int delb = (am == 40) ? 1 : 0;
    int repf = repb*vid;
    int insf = insb*vid*(((ln+insb) <= 15) ? 1 : 0);
    int delf = delb*vid*(((ln-delb) >  2) ? 1 : 0);
    int T = L_ - pos;
    int tail[13];
    for (int j=0;j<T;j++) tail[j] = st[bg*L_+pos+j];
    int aw = repw[((size_t)bg*NSTEP_+step)*40 + (am < 20 ? am : 19)];
    for (int j=0;j<T;j++){
      int rv = (j==0) ? aw : tail[j];
      int iv = (j==0) ? aw : tail[j-1];
      int dv = (j < T-1) ? tail[j+1] : PAD_;
      int hv = tail[j];
      int nv = repf ? rv : (insf ? iv : (delf ? dv : hv));
      st[bg*L_+pos+j] = nv;
    }
    len[bg] = ln + insf - delf;
    outPis[bg*NSTEP_+step]  = pi;
    outActs[bg*NSTEP_+step] = (float)am;
  }
}

__global__ void finalize(const int* st, const int* len, float* out){
  int gid = blockIdx.x*blockDim.x + threadIdx.x;
  if (gid < B_*L_)            out[2*B_*NSTEP_ + gid] = (float)st[gid];
  else if (gid < B_*L_ + B_)  out[2*B_*NSTEP_ + B_*L_ + (gid - B_*L_)] = (float)len[gid - B_*L_];
}

// ---------------------------------------------------------------- launch
extern "C" void kernel_launch(void* const* d_in, const int* in_sizes, int n_in,
                              void* d_out, int out_size, void* d_ws, size_t ws_size,
                              hipStream_t stream) {
  const int*   ids    = (const int*)  d_in[0];
  const float* keypos = (const float*)d_in[1];
  const int*   seqlen = (const int*)  d_in[2];
  const int*   repw   = (const int*)  d_in[3];
  const int*   valid  = (const int*)  d_in[4];
  const float* emb    = (const float*)d_in[5];
  const float* enc    = (const float*)d_in[6];
  const float* Wih0   = (const float*)d_in[7];
  const float* Whh0   = (const float*)d_in[8];
  const float* b0     = (const float*)d_in[9];
  const float* Wih1   = (const float*)d_in[10];
  const float* Whh1   = (const float*)d_in[11];
  const float* b1     = (const float*)d_in[12];
  const float* delv   = (const float*)d_in[13];
  const float* holdv  = (const float*)d_in[14];
  const float* mW     = (const float*)d_in[15];
  const float* mb     = (const float*)d_in[16];
  const float* m1W    = (const float*)d_in[17];
  const float* m1b    = (const float*)d_in[18];
  float* out = (float*)d_out;

  const size_t W0PD = (size_t)66*64*64*8;   // f16 per dir
  const size_t W1PD = (size_t)96*64*64*8;

  char* ws = (char*)d_ws;
  size_t off = 0;
  auto allocB = [&](size_t bytes) -> char* {
    char* pp = ws + off; off += (bytes + 255) & ~size_t(255); return pp;
  };
  f16*  Wf0h = (f16*)allocB(2*W0PD*2);
  f16*  Wf0l = (f16*)allocB(2*W0PD*2);
  f16*  Wf1h = (f16*)allocB(2*W1PD*2);
  f16*  Wf1l = (f16*)allocB(2*W1PD*2);
  float* bp0 = (float*)allocB(4096*4);
  float* bp1 = (float*)allocB(4096*4);
  f16*  embH = (f16*)allocB((size_t)VOC_*256*2);
  f16*  embL = (f16*)allocB((size_t)VOC_*256*2);
  float* mWt = (float*)allocB(104000*4);
  float* ep  = (float*)allocB((size_t)30007*100*4);
  int* stbuf  = (int*)allocB(B_*L_*4);
  int* lenbuf = (int*)allocB(B_*4);
  size_t fixedB = off;

  const int cands[6] = {4096, 2048, 1024, 512, 256, 128};
  int Bc = 0;
  for (int ci=0; ci<6; ++ci){
    size_t c = cands[ci];
    size_t chunkB = c*(size_t)(15*1024*2*2 + 4*512*2*2 + 2*512*4 + 2*512*4 + 1024*4) + 8*256;
    if (fixedB + chunkB <= ws_size){ Bc = (int)c; break; }
  }
  if (!Bc){
    float code = 100000.0f + (float)(ws_size >> 20);
    sentinel<<<(B_*NSTEP_+255)/256,256,0,stream>>>(out, code);
    return;
  }
  f16* o0h = (f16*)allocB((size_t)L_*Bc*1024*2);
  f16* o0l = (f16*)allocB((size_t)L_*Bc*1024*2);
  f16* h1h = (f16*)allocB((size_t)4*Bc*512*2);
  f16* h1l = (f16*)allocB((size_t)4*Bc*512*2);
  float* c0 = (float*)allocB((size_t)2*Bc*512*4);
  float* c1 = (float*)allocB((size_t)2*Bc*512*4);
  float* pooled = (float*)allocB((size_t)Bc*1024*4);

  prep_w0<<<(int)((2*W0PD+255)/256),256,0,stream>>>(Wih0, Whh0, b0, Wf0h, Wf0l, bp0);
  prep_w1<<<(int)((2*W1PD+255)/256),256,0,stream>>>(Wih1, Whh1, b1, Wf1h, Wf1l, bp1);
  prep_emb<<<(VOC_*256+255)/256,256,0,stream>>>(emb, embH, embL);
  prep_mlpwt<<<(100*1040+255)/256,256,0,stream>>>(mW, mWt);
  prep_encproj<<<30007,128,0,stream>>>(enc, delv, holdv, m1W, m1b, ep);
  init_st<<<(B_*L_+255)/256,256,0,stream>>>(ids, seqlen, stbuf, lenbuf);

  const int nblk = (Bc/128) * 32;

  for (int b0c=0; b0c<B_; b0c+=Bc){
    for (int step=0; step<NSTEP_; ++step){
      int pos = step + 2;   // i % 12 + 2 for i=0..4

      // ---- layer 0: full 15 timesteps, fw (t=ts) + bw (t=14-ts)
      for (int ts=0; ts<L_; ++ts){
        int tf = ts, tb = 14-ts;
        RecParams p{};
        p.gather = 1; p.t_0 = tf; p.t_1 = tb; p.pos = pos; p.b0c = b0c;
        p.embH = embH; p.embL = embL; p.st = stbuf; p.ids = ids;
        p.k1p = 17; p.k2p = ts ? 16 : 0;
        size_t of0 = (size_t)(ts?tf-1:0)*Bc*1024;
        size_t of1 = (size_t)(ts?tb+1:0)*Bc*1024 + (ts?512:0);
        p.A2h_0 = o0h + of0;  p.A2l_0 = o0l + of0;
        p.A2h_1 = o0h + of1;  p.A2l_1 = o0l + of1;
        p.lda2 = 1024;
        p.Wfh_0 = Wf0h;        p.Wfl_0 = Wf0l;
        p.Wfh_1 = Wf0h + W0PD; p.Wfl_1 = Wf0l + W0PD;
        p.bias_0 = bp0; p.bias_1 = bp0 + 2048;
        p.c_0 = c0; p.c_1 = c0 + (size_t)Bc*512;
        p.hh_0 = o0h + (size_t)tf*Bc*1024;       p.hl_0 = o0l + (size_t)tf*Bc*1024;
        p.hh_1 = o0h + (size_t)tb*Bc*1024 + 512; p.hl_1 = o0l + (size_t)tb*Bc*1024 + 512;
        p.ldh = 1024;
        p.h2_0 = nullptr; p.h2_1 = nullptr; p.ldh2 = 1024;
        p.first = (ts==0); p.act0 = 1; p.act1 = 1;
        rec_gemm<<<dim3(nblk),256,0,stream>>>(p);
      }

      // ---- layer 1: fw needs t<=pos only, bw needs t>=pos only
      int nL1 = L_ - pos;
      for (int ts=0; ts<nL1; ++ts){
        RecParams p{};
        int tf = ts, tb = 14-ts;
        int parR = (ts-1)&1, parW = ts&1;
        p.gather = 0;
        p.A1h_0 = o0h + (size_t)tf*Bc*1024;  p.A1l_0 = o0l + (size_t)tf*Bc*1024;
        p.A1h_1 = o0h + (size_t)tb*Bc*1024;  p.A1l_1 = o0l + (size_t)tb*Bc*1024;
        p.lda1 = 1024; p.k1p = 32;
        p.k2p  = ts ? 16 : 0;
        size_t r0 = (size_t)(0*2 + (ts?parR:0))*Bc*512;
        size_t r1 = (size_t)(1*2 + (ts?parR:0))*Bc*512;
        p.A2h_0 = h1h + r0; p.A2l_0 = h1l + r0;
        p.A2h_1 = h1h + r1; p.A2l_1 = h1l + r1;
        p.lda2 = 512;
        p.Wfh_0 = Wf1h;        p.Wfl_0 = Wf1l;
        p.Wfh_1 = Wf1h + W1PD; p.Wfl_1 = Wf1l + W1PD;
        p.bias_0 = bp1; p.bias_1 = bp1 + 2048;
        p.c_0 = c1; p.c_1 = c1 + (size_t)Bc*512;
        size_t w0 = (size_t)(0*2 + parW)*Bc*512;
        size_t w1 = (size_t)(1*2 + parW)*Bc*512;
        p.hh_0 = h1h + w0; p.hl_0 = h1l + w0;
        p.hh_1 = h1h + w1; p.hl_1 = h1l + w1;
        p.ldh = 512;
        p.h2_0 = (ts == pos)    ? pooled        : nullptr;
        p.h2_1 = (ts == 14-pos) ? (pooled+512)  : nullptr;
        p.ldh2 = 1024;
        p.first = (ts==0);
        p.act0 = (ts <= pos) ? 1 : 0; p.act1 = 1;
        rec_gemm<<<dim3(nblk),256,0,stream>>>(p);
      }

      score_update<<<Bc,128,0,stream>>>(pooled, keypos, mWt, mb, ep, m1W, repw, valid,
                                        stbuf, lenbuf, out, out + B_*NSTEP_, step, pos, b0c);
    }
  }
  finalize<<<(B_*L_+B_+255)/256,256,0,stream>>>(stbuf, lenbuf, out);
}

// Round 10
// 18887.135 us; speedup vs baseline: 1.1597x; 1.0693x over previous
//
#include <hip/hip_runtime.h>

#define B_ 4096
#define L_ 15
#define NSTEP_ 5
#define VOC_ 30005
#define PAD_ 30003

typedef _Float16 f16;
typedef f16  f16x8 __attribute__((ext_vector_type(8)));
typedef float f32x16 __attribute__((ext_vector_type(16)));

__device__ __forceinline__ float sigf(float x){ return 1.0f/(1.0f+expf(-x)); }

#define MFMA_(d,a,b) d = __builtin_amdgcn_mfma_f32_32x32x16_f16(a,b,d,0,0,0)

// ---------------------------------------------------------------- params
struct RecParams {
  const f16 *A1h_0,*A1l_0,*A1h_1,*A1l_1;   // x-part arrays (layer1 path)
  const f16 *A2h_0,*A2l_0,*A2h_1,*A2l_1;   // h-part arrays
  const f16 *Wfh_0,*Wfl_0,*Wfh_1,*Wfl_1;   // fragment-order W
  const float *bias_0,*bias_1;
  const f16 *embH,*embL;                   // split emb table (gather mode)
  const int *st,*ids;
  float *c_0,*c_1,*h2_0,*h2_1;
  f16 *hh_0,*hl_0,*hh_1,*hl_1;
  int lda1, lda2, ldh, ldh2, k1p, k2p, first, gather, t_0, t_1, pos, b0c, act0, act1;
};

// swizzled byte offset into a [128 rows][16 k] f16 (4KB) LDS array (Gray).
__device__ __forceinline__ int swz(int row, int s){
  int u = ((row&7)<<1) | s;
  return ((row>>3)<<8) + ((u ^ (u>>1))<<4);
}

// --------------------------------- fused split-f16 MFMA GEMM + LSTM cell
// 128x256 output tile per block, 512 threads (8 waves), 1 block/CU.
// Wave w: row-half rh=w&1 (64 rows), col-quarter cq=w>>1 (64 cols) -> same
// validated 2x2 32x32-tile quad per wave as R6. B-fragments from global
// (fragment-linear Wf): rh-paired waves load IDENTICAL B -> L1 dedup; per-CU
// B traffic per phase halves vs the 128x128 tile. A staged in LDS (Gray swz).
__global__ __launch_bounds__(512,2) void rec_gemm(RecParams p){
  const int bxe = blockIdx.x;
  const int ct8 = bxe & 7;           // 256-col group (0..7)
  const int dir = bxe >> 3;          // 0 = fw, 1 = bw
  if (!(dir ? p.act1 : p.act0)) return;
  const f16* A1h = dir ? p.A1h_1 : p.A1h_0;
  const f16* A1l = dir ? p.A1l_1 : p.A1l_0;
  const f16* A2h = dir ? p.A2h_1 : p.A2h_0;
  const f16* A2l = dir ? p.A2l_1 : p.A2l_0;
  const f16* Wfh = dir ? p.Wfh_1 : p.Wfh_0;
  const f16* Wfl = dir ? p.Wfl_1 : p.Wfl_0;
  const float* bias = dir ? p.bias_1 : p.bias_0;
  float* cbuf = dir ? p.c_1 : p.c_0;
  float* h2   = dir ? p.h2_1 : p.h2_0;
  f16* hhb = dir ? p.hh_1 : p.hh_0;
  f16* hlb = dir ? p.hl_1 : p.hl_0;
  const int tcur = dir ? p.t_1 : p.t_0;

  const int tid  = threadIdx.x;
  const int lane = tid & 63;
  const int w    = tid >> 6;         // 0..7
  const int mbase = blockIdx.y*128;

  __shared__ union {
    float z[128*128];          // 64 KB epilogue (used twice, col-halves)
    f16   stg[8][2048];        // [buf*4 + {s0h,s0l,s1h,s1l}] 4KB each
  } sm;

  f32x16 accM[2][2], accX[2][2];
#pragma unroll
  for (int i=0;i<2;i++)
#pragma unroll
    for (int j=0;j<2;j++)
#pragma unroll
      for (int r=0;r<16;r++){ accM[i][j][r]=0.f; accX[i][j][r]=0.f; }

  // a-frag read offsets (validated scheme, per 4KB sub-array)
  const int arow = (w&1)*64 + (lane&31);
  const int fs = lane>>5;
  const int aoff0 = swz(arow,    fs), aoff1 = swz(arow+32, fs);

  // b-frag global fragment pointers: wave covers 2 ct units (64 cols)
  const int ct0 = ct8*8 + (w>>1)*2;
  const f16* WfhL = Wfh + (size_t)lane*8;
  const f16* WflL = Wfl + (size_t)lane*8;

  // A staging: 512 threads, each stages one 16B unit in 2 arrays (h,l) of
  // its k-subtile pair pr; (srow,ss) from Gray-swizzled unit index.
  const int u = tid & 255, pr = tid >> 8;
  const int srow = u >> 1, ss = u & 1;
  const int sws = swz(srow, ss);
  const int kph = pr*16 + ss*8;      // k offset within the 32-wide phase
  const int ktot = p.k1p + p.k2p;

  // gather-mode hoisted tokens
  int tokT=0, tokI=0, zflag=0;
  if (p.gather){
    int gb = p.b0c + mbase + srow;
    tokT = p.st [gb*L_ + tcur];
    tokI = p.ids[gb*L_ + tcur];
    zflag = (tcur == p.pos) ? 1 : 0;
  }

  f16x8 ra_h, ra_l;
  const f16x8 zero8 = {0,0,0,0,0,0,0,0};

  auto gload = [&](int ph){
    if (ph >= ktot) return;
    if (ph < p.k1p){
      if (p.gather){
        if (ph < 8){                     // embt part (cols 0..255)
          if (zflag){ ra_h=zero8; ra_l=zero8; }
          else {
            size_t base = (size_t)tokT*256 + ph*32 + kph;
            ra_h = *(const f16x8*)(p.embH + base);
            ra_l = *(const f16x8*)(p.embL + base);
          }
        } else if (ph < 16){             // emb0 part (cols 256..511)
          size_t base = (size_t)tokI*256 + (ph-8)*32 + kph;
          ra_h = *(const f16x8*)(p.embH + base);
          ra_l = *(const f16x8*)(p.embL + base);
        } else {                         // ph==16: posflag @512, rest 0
          ra_h = zero8; ra_l = zero8;
          if (kph == 0) ra_h[0] = zflag ? (f16)1.0f : (f16)0.0f;
        }
      } else {
        long base = (long)(mbase+srow)*p.lda1 + ph*32 + kph;
        ra_h = *(const f16x8*)(A1h + base);
        ra_l = *(const f16x8*)(A1l + base);
      }
    } else {
      long base = (long)(mbase+srow)*p.lda2 + (ph - p.k1p)*32 + kph;
      ra_h = *(const f16x8*)(A2h + base);
      ra_l = *(const f16x8*)(A2l + base);
    }
  };
  auto swrite = [&](int buf){
    *(f16x8*)((char*)sm.stg[buf*4 + pr*2 + 0] + sws) = ra_h;
    *(f16x8*)((char*)sm.stg[buf*4 + pr*2 + 1] + sws) = ra_l;
  };

  gload(0); swrite(0); gload(1);
  __syncthreads();

  for (int ph=0; ph<ktot; ++ph){
    const int cur = ph & 1;
    // B fragments for this phase (global, L1-dedup'd across rh-paired waves)
    size_t base0 = ((size_t)(ph*2+0)*64 + ct0)*512;
    size_t base1 = ((size_t)(ph*2+1)*64 + ct0)*512;
    f16x8 rbh00 = *(const f16x8*)(WfhL + base0);
    f16x8 rbh01 = *(const f16x8*)(WfhL + base0 + 512);
    f16x8 rbl00 = *(const f16x8*)(WflL + base0);
    f16x8 rbl01 = *(const f16x8*)(WflL + base0 + 512);
    f16x8 rbh10 = *(const f16x8*)(WfhL + base1);
    f16x8 rbh11 = *(const f16x8*)(WfhL + base1 + 512);
    f16x8 rbl10 = *(const f16x8*)(WflL + base1);
    f16x8 rbl11 = *(const f16x8*)(WflL + base1 + 512);
    // A fragments from LDS
    const char* s0h = (const char*)sm.stg[cur*4+0];
    const char* s0l = (const char*)sm.stg[cur*4+1];
    const char* s1h = (const char*)sm.stg[cur*4+2];
    const char* s1l = (const char*)sm.stg[cur*4+3];
    f16x8 a00h = *(const f16x8*)(s0h + aoff0);
    f16x8 a01h = *(const f16x8*)(s0h + aoff1);
    f16x8 a00l = *(const f16x8*)(s0l + aoff0);
    f16x8 a01l = *(const f16x8*)(s0l + aoff1);
    f16x8 a10h = *(const f16x8*)(s1h + aoff0);
    f16x8 a11h = *(const f16x8*)(s1h + aoff1);
    f16x8 a10l = *(const f16x8*)(s1l + aoff0);
    f16x8 a11l = *(const f16x8*)(s1l + aoff1);
    // stage next A tile (values loaded last phase), issue A(ph+2)
    if (ph+1 < ktot){ swrite((ph+1)&1); gload(ph+2); }
    // sub0
    MFMA_(accM[0][0], a00h, rbh00); MFMA_(accX[0][0], a00h, rbl00); MFMA_(accX[0][0], a00l, rbh00);
    MFMA_(accM[1][0], a01h, rbh00); MFMA_(accX[1][0], a01h, rbl00); MFMA_(accX[1][0], a01l, rbh00);
    MFMA_(accM[0][1], a00h, rbh01); MFMA_(accX[0][1], a00h, rbl01); MFMA_(accX[0][1], a00l, rbh01);
    MFMA_(accM[1][1], a01h, rbh01); MFMA_(accX[1][1], a01h, rbl01); MFMA_(accX[1][1], a01l, rbh01);
    // sub1
    MFMA_(accM[0][0], a10h, rbh10); MFMA_(accX[0][0], a10h, rbl10); MFMA_(accX[0][0], a10l, rbh10);
    MFMA_(accM[1][0], a11h, rbh10); MFMA_(accX[1][0], a11h, rbl10); MFMA_(accX[1][0], a11l, rbh10);
    MFMA_(accM[0][1], a10h, rbh11); MFMA_(accX[0][1], a10h, rbl11); MFMA_(accX[0][1], a10l, rbh11);
    MFMA_(accM[1][1], a11h, rbh11); MFMA_(accX[1][1], a11h, rbl11); MFMA_(accX[1][1], a11l, rbh11);
    __syncthreads();
  }

  // ---- epilogue: two col-halves; z (128x128) -> LDS regroup -> LSTM cell
  const int cq = w >> 1;
  for (int hf=0; hf<2; ++hf){
    if ((cq>>1) == hf){
#pragma unroll
      for (int tm=0;tm<2;tm++)
#pragma unroll
       for (int tn=0;tn<2;tn++){
        int lcol = (cq&1)*64 + tn*32 + (lane&31);
        float bv = bias[ct8*256 + hf*128 + lcol];
#pragma unroll
        for (int r=0;r<16;r++){
          int lrow = (w&1)*64 + tm*32 + (r&3) + 8*(r>>2) + 4*(lane>>5);
          sm.z[lrow*128 + lcol] = accM[tm][tn][r] + 0.000244140625f*accX[tm][tn][r] + bv;
        }
       }
    }
    __syncthreads();
    const int nb = ct8*64 + hf*32;
#pragma unroll
    for (int it=0; it<8; ++it){
      int idx = it*512 + tid;
      int nq = idx & 31, row = idx >> 5;
      float4 g4 = *(const float4*)&sm.z[row*128 + nq*4];
      int m = mbase + row, n = nb + nq;
      float cp = p.first ? 0.f : cbuf[(size_t)m*512 + n];
      float cc = sigf(g4.y)*cp + sigf(g4.x)*tanhf(g4.z);
      float hv = sigf(g4.w)*tanhf(cc);
      cbuf[(size_t)m*512 + n] = cc;
      f16 hi = (f16)hv;
      f16 lo = (f16)((hv - (float)hi)*4096.0f);
      hhb[(size_t)m*p.ldh + n] = hi;
      hlb[(size_t)m*p.ldh + n] = lo;
      if (h2) h2[(size_t)m*p.ldh2 + n] = hv;
    }
    __syncthreads();
  }
}

// ------------------------------------------- prep: W in MFMA fragment order
__global__ void prep_w0(const float* Wih, const float* Whh, const float* b0,
                        f16* Wfh, f16* Wfl, float* bp){
  int gid = blockIdx.x*blockDim.x + threadIdx.x;
  const int PER_DIR = 66*64*64*8;
  if (gid >= 2*PER_DIR) return;
  int dir = gid / PER_DIR;
  int rem = gid % PER_DIR;
  int j = rem & 7, lane = (rem>>3)&63, ct = (rem>>9)&63, kt16 = rem>>15;
  int n4g = ct*32 + (lane&31);
  int n = n4g>>2, g = n4g&3;
  int srow = dir*2048 + g*512 + n;
  int k = kt16*16 + ((lane>>5)<<3) + j;     // padded K: [Wih 513 | pad 31 | Whh 512]
  float v;
  if (k < 513)       v = Wih[(size_t)srow*513 + k];
  else if (k < 544)  v = 0.f;
  else               v = Whh[(size_t)srow*512 + (k-544)];
  f16 hi = (f16)v;
  Wfh[gid] = hi;
  Wfl[gid] = (f16)((v - (float)hi)*4096.0f);
  if (kt16==0 && (lane>>5)==0 && j==0) bp[dir*2048 + n4g] = b0[srow];
}

__global__ void prep_w1(const float* Wih, const float* Whh, const float* b1,
                        f16* Wfh, f16* Wfl, float* bp){
  int gid = blockIdx.x*blockDim.x + threadIdx.x;
  const int PER_DIR = 96*64*64*8;
  if (gid >= 2*PER_DIR) return;
  int dir = gid / PER_DIR;
  int rem = gid % PER_DIR;
  int j = rem & 7, lane = (rem>>3)&63, ct = (rem>>9)&63, kt16 = rem>>15;
  int n4g = ct*32 + (lane&31);
  int n = n4g>>2, g = n4g&3;
  int srow = dir*2048 + g*512 + n;
  int k = kt16*16 + ((lane>>5)<<3) + j;     // [Wih 1024 | Whh 512]
  float v;
  if (k < 1024) v = Wih[(size_t)srow*1024 + k];
  else          v = Whh[(size_t)srow*512 + (k-1024)];
  f16 hi = (f16)v;
  Wfh[gid] = hi;
  Wfl[gid] = (f16)((v - (float)hi)*4096.0f);
  if (kt16==0 && (lane>>5)==0 && j==0) bp[dir*2048 + n4g] = b1[srow];
}

__global__ void prep_emb(const float* emb, f16* eh, f16* el){
  int gid = blockIdx.x*blockDim.x + threadIdx.x;
  if (gid >= VOC_*256) return;
  float v = emb[gid];
  f16 hi = (f16)v;
  eh[gid] = hi;
  el[gid] = (f16)((v - (float)hi)*4096.0f);
}

__global__ void prep_mlpwt(const float* mW, float* wt){
  int gid = blockIdx.x*blockDim.x + threadIdx.x;
  if (gid >= 100*1040) return;
  int j = gid / 1040, k = gid % 1040;
  wt[k*100 + j] = mW[gid];
}

__global__ __launch_bounds__(128) void prep_encproj(const float* enc, const float* delv,
                        const float* holdv, const float* m1W, const float* m1b, float* ep){
  int r = blockIdx.x;
  __shared__ float row[256];
  const float* src = (r < VOC_) ? enc + (size_t)r*256 : (r == VOC_ ? delv : holdv);
  for (int i=threadIdx.x;i<256;i+=128) row[i]=src[i];
  __syncthreads();
  int j = threadIdx.x;
  if (j < 100){
    double s = (double)m1b[j];
    const float* wr = m1W + (size_t)j*298;
    for (int k=0;k<256;k++) s += (double)wr[k] * (double)row[k];
    ep[(size_t)r*100 + j] = (float)s;
  }
}

__global__ void init_st(const int* ids, const int* seqlen, int* st, int* len){
  int gid = blockIdx.x*blockDim.x + threadIdx.x;
  if (gid < B_*L_) st[gid] = ids[gid];
  if (gid < B_)    len[gid] = seqlen[gid];
}

__global__ void sentinel(float* out, float v){
  int gid = blockIdx.x*blockDim.x + threadIdx.x;
  if (gid < B_*NSTEP_) out[gid] = v;
}

// ------------------------------------------------- scoring + sequence edit
__global__ __launch_bounds__(128) void score_update(
    const float* pooled, const float* keypos, const float* mWt, const float* mb,
    const float* ep, const float* m1W, const int* repw, const int* valid,
    int* st, int* len, float* outPis, float* outActs, int step, int pos, int b0){
  int b = blockIdx.x;
  int bg = b0 + b;
  __shared__ float rep[1040];
  __shared__ float r100[100];
  __shared__ double sc[42];
  int tid = threadIdx.x;
  for (int i=tid;i<1024;i+=128) rep[i] = pooled[(size_t)b*1024+i];
  if (tid < 16){
    if (tid == 0) rep[1024] = keypos[bg*L_+pos];
    else          rep[1024+tid] = ((tid-1)==pos) ? 1.f : 0.f;
  }
  __syncthreads();
  if (tid < 100){
    double s = (double)mb[tid];
    for (int k=0;k<1040;k++) s += (double)mWt[k*100+tid] * (double)rep[k];
    r100[tid] = (float)s;
  }
  __syncthreads();
  if (tid < 42){
    int row = (tid < 40) ? repw[((size_t)bg*NSTEP_+step)*40 + tid] : (VOC_ + (tid-40));
    const float* er = ep + (size_t)row*100;
    double s = 0.0;
    for (int j=0;j<100;j++) s += (double)er[j] * (double)r100[j];
    for (int j=0;j<100;j++) s += (double)m1W[j*298 + 256 + tid] * (double)r100[j];
    sc[tid] = s;
  }
  __syncthreads();
  if (tid == 0){
    double mx = sc[0]; int am = 0;
    for (int k=1;k<42;k++) if (sc[k] > mx){ mx = sc[k]; am = k; }
    double sum = 0.0;
    for (int k=0;k<42;k++) sum += exp(sc[k]-mx);
    float pi = (float)(1.0/sum);
    int vid = valid[bg*NSTEP_+step];
    int ln  = len[bg];
    int repb = (am < 20) ? 1 : 0;
    int insb = (am >= 20 && am < 40) ? 1 : 0;
    int delb = (am == 40) ? 1 : 0;
    int repf = repb*vid;
    int insf = insb*vid*(((ln+insb) <= 15) ? 1 : 0);
    int delf = delb*vid*(((ln-delb) >  2) ? 1 : 0);
    int T = L_ - pos;
    int tail[13];
    for (int j=0;j<T;j++) tail[j] = st[bg*L_+pos+j];
    int aw = repw[((size_t)bg*NSTEP_+step)*40 + (am < 20 ? am : 19)];
    for (int j=0;j<T;j++){
      int rv = (j==0) ? aw : tail[j];
      int iv = (j==0) ? aw : tail[j-1];
      int dv = (j < T-1) ? tail[j+1] : PAD_;
      int hv = tail[j];
      int nv = repf ? rv : (insf ? iv : (delf ? dv : hv));
      st[bg*L_+pos+j] = nv;
    }
    len[bg] = ln + insf - delf;
    outPis[bg*NSTEP_+step]  = pi;
    outActs[bg*NSTEP_+step] = (float)am;
  }
}

__global__ void finalize(const int* st, const int* len, float* out){
  int gid = blockIdx.x*blockDim.x + threadIdx.x;
  if (gid < B_*L_)            out[2*B_*NSTEP_ + gid] = (float)st[gid];
  else if (gid < B_*L_ + B_)  out[2*B_*NSTEP_ + B_*L_ + (gid - B_*L_)] = (float)len[gid - B_*L_];
}

// ---------------------------------------------------------------- launch
extern "C" void kernel_launch(void* const* d_in, const int* in_sizes, int n_in,
                              void* d_out, int out_size, void* d_ws, size_t ws_size,
                              hipStream_t stream) {
  const int*   ids    = (const int*)  d_in[0];
  const float* keypos = (const float*)d_in[1];
  const int*   seqlen = (const int*)  d_in[2];
  const int*   repw   = (const int*)  d_in[3];
  const int*   valid  = (const int*)  d_in[4];
  const float* emb    = (const float*)d_in[5];
  const float* enc    = (const float*)d_in[6];
  const float* Wih0   = (const float*)d_in[7];
  const float* Whh0   = (const float*)d_in[8];
  const float* b0     = (const float*)d_in[9];
  const float* Wih1   = (const float*)d_in[10];
  const float* Whh1   = (const float*)d_in[11];
  const float* b1     = (const float*)d_in[12];
  const float* delv   = (const float*)d_in[13];
  const float* holdv  = (const float*)d_in[14];
  const float* mW     = (const float*)d_in[15];
  const float* mb     = (const float*)d_in[16];
  const float* m1W    = (const float*)d_in[17];
  const float* m1b    = (const float*)d_in[18];
  float* out = (float*)d_out;

  const size_t W0PD = (size_t)66*64*64*8;   // f16 per dir
  const size_t W1PD = (size_t)96*64*64*8;

  char* ws = (char*)d_ws;
  size_t off = 0;
  auto allocB = [&](size_t bytes) -> char* {
    char* pp = ws + off; off += (bytes + 255) & ~size_t(255); return pp;
  };
  f16*  Wf0h = (f16*)allocB(2*W0PD*2);
  f16*  Wf0l = (f16*)allocB(2*W0PD*2);
  f16*  Wf1h = (f16*)allocB(2*W1PD*2);
  f16*  Wf1l = (f16*)allocB(2*W1PD*2);
  float* bp0 = (float*)allocB(4096*4);
  float* bp1 = (float*)allocB(4096*4);
  f16*  embH = (f16*)allocB((size_t)VOC_*256*2);
  f16*  embL = (f16*)allocB((size_t)VOC_*256*2);
  float* mWt = (float*)allocB(104000*4);
  float* ep  = (float*)allocB((size_t)30007*100*4);
  int* stbuf  = (int*)allocB(B_*L_*4);
  int* lenbuf = (int*)allocB(B_*4);
  size_t fixedB = off;

  const int cands[6] = {4096, 2048, 1024, 512, 256, 128};
  int Bc = 0;
  for (int ci=0; ci<6; ++ci){
    size_t c = cands[ci];
    size_t chunkB = c*(size_t)(15*1024*2*2 + 4*512*2*2 + 2*512*4 + 2*512*4 + 1024*4) + 8*256;
    if (fixedB + chunkB <= ws_size){ Bc = (int)c; break; }
  }
  if (!Bc){
    float code = 100000.0f + (float)(ws_size >> 20);
    sentinel<<<(B_*NSTEP_+255)/256,256,0,stream>>>(out, code);
    return;
  }
  f16* o0h = (f16*)allocB((size_t)L_*Bc*1024*2);
  f16* o0l = (f16*)allocB((size_t)L_*Bc*1024*2);
  f16* h1h = (f16*)allocB((size_t)4*Bc*512*2);
  f16* h1l = (f16*)allocB((size_t)4*Bc*512*2);
  float* c0 = (float*)allocB((size_t)2*Bc*512*4);
  float* c1 = (float*)allocB((size_t)2*Bc*512*4);
  float* pooled = (float*)allocB((size_t)Bc*1024*4);

  prep_w0<<<(int)((2*W0PD+255)/256),256,0,stream>>>(Wih0, Whh0, b0, Wf0h, Wf0l, bp0);
  prep_w1<<<(int)((2*W1PD+255)/256),256,0,stream>>>(Wih1, Whh1, b1, Wf1h, Wf1l, bp1);
  prep_emb<<<(VOC_*256+255)/256,256,0,stream>>>(emb, embH, embL);
  prep_mlpwt<<<(100*1040+255)/256,256,0,stream>>>(mW, mWt);
  prep_encproj<<<30007,128,0,stream>>>(enc, delv, holdv, m1W, m1b, ep);
  init_st<<<(B_*L_+255)/256,256,0,stream>>>(ids, seqlen, stbuf, lenbuf);

  for (int b0c=0; b0c<B_; b0c+=Bc){
    for (int step=0; step<NSTEP_; ++step){
      int pos = step + 2;   // i % 12 + 2 for i=0..4

      // ---- layer 0: full 15 timesteps, fw (t=ts) + bw (t=14-ts)
      for (int ts=0; ts<L_; ++ts){
        int tf = ts, tb = 14-ts;
        RecParams p{};
        p.gather = 1; p.t_0 = tf; p.t_1 = tb; p.pos = pos; p.b0c = b0c;
        p.embH = embH; p.embL = embL; p.st = stbuf; p.ids = ids;
        p.k1p = 17; p.k2p = ts ? 16 : 0;
        size_t of0 = (size_t)(ts?tf-1:0)*Bc*1024;
        size_t of1 = (size_t)(ts?tb+1:0)*Bc*1024 + (ts?512:0);
        p.A2h_0 = o0h + of0;  p.A2l_0 = o0l + of0;
        p.A2h_1 = o0h + of1;  p.A2l_1 = o0l + of1;
        p.lda2 = 1024;
        p.Wfh_0 = Wf0h;        p.Wfl_0 = Wf0l;
        p.Wfh_1 = Wf0h + W0PD; p.Wfl_1 = Wf0l + W0PD;
        p.bias_0 = bp0; p.bias_1 = bp0 + 2048;
        p.c_0 = c0; p.c_1 = c0 + (size_t)Bc*512;
        p.hh_0 = o0h + (size_t)tf*Bc*1024;       p.hl_0 = o0l + (size_t)tf*Bc*1024;
        p.hh_1 = o0h + (size_t)tb*Bc*1024 + 512; p.hl_1 = o0l + (size_t)tb*Bc*1024 + 512;
        p.ldh = 1024;
        p.h2_0 = nullptr; p.h2_1 = nullptr; p.ldh2 = 1024;
        p.first = (ts==0); p.act0 = 1; p.act1 = 1;
        rec_gemm<<<dim3(16,Bc/128),512,0,stream>>>(p);
      }

      // ---- layer 1: fw needs t<=pos only, bw needs t>=pos only
      int nL1 = L_ - pos;
      for (int ts=0; ts<nL1; ++ts){
        RecParams p{};
        int tf = ts, tb = 14-ts;
        int parR = (ts-1)&1, parW = ts&1;
        p.gather = 0;
        p.A1h_0 = o0h + (size_t)tf*Bc*1024;  p.A1l_0 = o0l + (size_t)tf*Bc*1024;
        p.A1h_1 = o0h + (size_t)tb*Bc*1024;  p.A1l_1 = o0l + (size_t)tb*Bc*1024;
        p.lda1 = 1024; p.k1p = 32;
        p.k2p  = ts ? 16 : 0;
        size_t r0 = (size_t)(0*2 + (ts?parR:0))*Bc*512;
        size_t r1 = (size_t)(1*2 + (ts?parR:0))*Bc*512;
        p.A2h_0 = h1h + r0; p.A2l_0 = h1l + r0;
        p.A2h_1 = h1h + r1; p.A2l_1 = h1l + r1;
        p.lda2 = 512;
        p.Wfh_0 = Wf1h;        p.Wfl_0 = Wf1l;
        p.Wfh_1 = Wf1h + W1PD; p.Wfl_1 = Wf1l + W1PD;
        p.bias_0 = bp1; p.bias_1 = bp1 + 2048;
        p.c_0 = c1; p.c_1 = c1 + (size_t)Bc*512;
        size_t w0 = (size_t)(0*2 + parW)*Bc*512;
        size_t w1 = (size_t)(1*2 + parW)*Bc*512;
        p.hh_0 = h1h + w0; p.hl_0 = h1l + w0;
        p.hh_1 = h1h + w1; p.hl_1 = h1l + w1;
        p.ldh = 512;
        p.h2_0 = (ts == pos)    ? pooled        : nullptr;
        p.h2_1 = (ts == 14-pos) ? (pooled+512)  : nullptr;
        p.ldh2 = 1024;
        p.first = (ts==0);
        p.act0 = (ts <= pos) ? 1 : 0; p.act1 = 1;
        rec_gemm<<<dim3(16,Bc/128),512,0,stream>>>(p);
      }

      score_update<<<Bc,128,0,stream>>>(pooled, keypos, mWt, mb, ep, m1W, repw, valid,
                                        stbuf, lenbuf, out, out + B_*NSTEP_, step, pos, b0c);
    }
  }
  finalize<<<(B_*L_+B_+255)/256,256,0,stream>>>(stbuf, lenbuf, out);
}

// Round 11
// 18610.457 us; speedup vs baseline: 1.1769x; 1.0149x over previous
//
#include <hip/hip_runtime.h>

#define B_ 4096
#define L_ 15
#define NSTEP_ 5
#define VOC_ 30005
#define PAD_ 30003

typedef _Float16 f16;
typedef f16  f16x8 __attribute__((ext_vector_type(8)));
typedef float f32x16 __attribute__((ext_vector_type(16)));

__device__ __forceinline__ float sigf(float x){ return 1.0f/(1.0f+expf(-x)); }

#define MFMA_(d,a,b) d = __builtin_amdgcn_mfma_f32_32x32x16_f16(a,b,d,0,0,0)

// ---------------------------------------------------------------- params
struct RecParams {
  const f16 *A1h_0,*A1l_0,*A1h_1,*A1l_1;   // x-part arrays (layer1 path)
  const f16 *A2h_0,*A2l_0,*A2h_1,*A2l_1;   // h-part arrays
  const f16 *Wfh_0,*Wfl_0,*Wfh_1,*Wfl_1;   // fragment-order W
  const float *bias_0,*bias_1;
  const f16 *embH,*embL;                   // split emb table (gather mode)
  const int *st,*ids;
  float *c_0,*c_1,*h2_0,*h2_1;
  f16 *hh_0,*hl_0,*hh_1,*hl_1;
  int lda1, lda2, ldh, ldh2, k1p, k2p, first, gather, t_0, t_1, pos, b0c, act0, act1;
};

// swizzled byte offset into a [128 rows][16 k] f16 (4KB) LDS sub-array (Gray).
__device__ __forceinline__ int swz(int row, int s){
  int u = ((row&7)<<1) | s;
  return ((row>>3)<<8) + ((u ^ (u>>1))<<4);
}

// --------------------------------- fused split-f16 MFMA GEMM + LSTM cell
// 128x256 output tile, 512 threads (8 waves). BK=64 per phase (4 k16
// subtiles, 48 MFMA/wave) -> HALF the barriers/vmcnt-drains of the BK=32
// structure; per-phase fixed overhead (latency drain + barrier) amortized.
// LDS: 2 buffers x 8 sub-arrays(4KB) = 64KB, union'd with the z epilogue.
__global__ __launch_bounds__(512,2) void rec_gemm(RecParams p){
  const int bxe = blockIdx.x;
  const int ct8 = bxe & 7;           // 256-col group (0..7)
  const int dir = bxe >> 3;          // 0 = fw, 1 = bw
  if (!(dir ? p.act1 : p.act0)) return;
  const f16* A1h = dir ? p.A1h_1 : p.A1h_0;
  const f16* A1l = dir ? p.A1l_1 : p.A1l_0;
  const f16* A2h = dir ? p.A2h_1 : p.A2h_0;
  const f16* A2l = dir ? p.A2l_1 : p.A2l_0;
  const f16* Wfh = dir ? p.Wfh_1 : p.Wfh_0;
  const f16* Wfl = dir ? p.Wfl_1 : p.Wfl_0;
  const float* bias = dir ? p.bias_1 : p.bias_0;
  float* cbuf = dir ? p.c_1 : p.c_0;
  float* h2   = dir ? p.h2_1 : p.h2_0;
  f16* hhb = dir ? p.hh_1 : p.hh_0;
  f16* hlb = dir ? p.hl_1 : p.hl_0;
  const int tcur = dir ? p.t_1 : p.t_0;

  const int tid  = threadIdx.x;
  const int lane = tid & 63;
  const int w    = tid >> 6;         // 0..7
  const int mbase = blockIdx.y*128;

  __shared__ union {
    float z[128*128];          // 64 KB epilogue (used twice, col-halves)
    f16   stg[2][8][2048];     // [buf][kq*2 + {h,l}] 4KB sub-arrays
  } sm;

  f32x16 accM[2][2], accX[2][2];
#pragma unroll
  for (int i=0;i<2;i++)
#pragma unroll
    for (int j=0;j<2;j++)
#pragma unroll
      for (int r=0;r<16;r++){ accM[i][j][r]=0.f; accX[i][j][r]=0.f; }

  // a-frag read offsets (validated scheme, per 4KB sub-array)
  const int arow = (w&1)*64 + (lane&31);
  const int fs = lane>>5;
  const int aoff0 = swz(arow,    fs), aoff1 = swz(arow+32, fs);

  // b-frag global fragment pointers: wave covers 2 ct units (64 cols)
  const int ct0 = ct8*8 + (w>>1)*2;
  const f16* WfhL = Wfh + (size_t)lane*8;
  const f16* WflL = Wfl + (size_t)lane*8;

  // A staging: 512 threads; thread (u=tid&255 -> srow=u>>1, ss=u&1; pr=tid>>8)
  // loads 32B contiguous (2x16B units: kq=2pr slot ss, kq=2pr+1 slot ss) for
  // both h and l arrays -> 4x16B per thread per BK64 phase.
  const int u = tid & 255, pr = tid >> 8;
  const int srow = u >> 1, ss = u & 1;
  const int sws = swz(srow, ss);
  const int koffT = pr*32 + ss*8;    // thread's k offset within the 64-wide phase
  const int ktot = p.k1p + p.k2p;

  // gather-mode hoisted tokens
  int tokT=0, tokI=0, zflag=0;
  if (p.gather){
    int gb = p.b0c + mbase + srow;
    tokT = p.st [gb*L_ + tcur];
    tokI = p.ids[gb*L_ + tcur];
    zflag = (tcur == p.pos) ? 1 : 0;
  }

  f16x8 ra_h0, ra_l0, ra_h1, ra_l1;
  const f16x8 zero8 = {0,0,0,0,0,0,0,0};

  auto gload = [&](int ph){
    if (ph >= ktot) return;
    if (ph < p.k1p){
      if (p.gather){
        if (ph < 4){                     // embt part (k 0..255)
          if (zflag){ ra_h0=zero8; ra_l0=zero8; ra_h1=zero8; ra_l1=zero8; }
          else {
            size_t base = (size_t)tokT*256 + ph*64 + koffT;
            ra_h0 = *(const f16x8*)(p.embH + base);
            ra_l0 = *(const f16x8*)(p.embL + base);
            ra_h1 = *(const f16x8*)(p.embH + base + 16);
            ra_l1 = *(const f16x8*)(p.embL + base + 16);
          }
        } else if (ph < 8){              // emb0 part (k 256..511)
          size_t base = (size_t)tokI*256 + (ph-4)*64 + koffT;
          ra_h0 = *(const f16x8*)(p.embH + base);
          ra_l0 = *(const f16x8*)(p.embL + base);
          ra_h1 = *(const f16x8*)(p.embH + base + 16);
          ra_l1 = *(const f16x8*)(p.embL + base + 16);
        } else {                         // ph==8: k 512..575, posflag @512
          ra_h0 = zero8; ra_l0 = zero8; ra_h1 = zero8; ra_l1 = zero8;
          if (pr==0 && ss==0) ra_h0[0] = zflag ? (f16)1.0f : (f16)0.0f;
        }
      } else {
        long base = (long)(mbase+srow)*p.lda1 + ph*64 + koffT;
        ra_h0 = *(const f16x8*)(A1h + base);
        ra_l0 = *(const f16x8*)(A1l + base);
        ra_h1 = *(const f16x8*)(A1h + base + 16);
        ra_l1 = *(const f16x8*)(A1l + base + 16);
      }
    } else {
      long base = (long)(mbase+srow)*p.lda2 + (ph - p.k1p)*64 + koffT;
      ra_h0 = *(const f16x8*)(A2h + base);
      ra_l0 = *(const f16x8*)(A2l + base);
      ra_h1 = *(const f16x8*)(A2h + base + 16);
      ra_l1 = *(const f16x8*)(A2l + base + 16);
    }
  };
  auto swrite = [&](int buf){
    *(f16x8*)((char*)sm.stg[buf][4*pr+0] + sws) = ra_h0;   // kq=2pr,   h
    *(f16x8*)((char*)sm.stg[buf][4*pr+1] + sws) = ra_l0;   // kq=2pr,   l
    *(f16x8*)((char*)sm.stg[buf][4*pr+2] + sws) = ra_h1;   // kq=2pr+1, h
    *(f16x8*)((char*)sm.stg[buf][4*pr+3] + sws) = ra_l1;   // kq=2pr+1, l
  };

  gload(0); swrite(0); gload(1);
  __syncthreads();

  for (int ph=0; ph<ktot; ++ph){
    const int cur = ph & 1;
#pragma unroll
    for (int kq=0; kq<4; ++kq){
      const char* sh = (const char*)sm.stg[cur][kq*2+0];
      const char* sl = (const char*)sm.stg[cur][kq*2+1];
      f16x8 a0h = *(const f16x8*)(sh + aoff0);
      f16x8 a1h = *(const f16x8*)(sh + aoff1);
      f16x8 a0l = *(const f16x8*)(sl + aoff0);
      f16x8 a1l = *(const f16x8*)(sl + aoff1);
      size_t base = ((size_t)(ph*4+kq)*64 + ct0)*512;
      f16x8 bh0 = *(const f16x8*)(WfhL + base);
      f16x8 bh1 = *(const f16x8*)(WfhL + base + 512);
      f16x8 bl0 = *(const f16x8*)(WflL + base);
      f16x8 bl1 = *(const f16x8*)(WflL + base + 512);
      if (kq == 1){ if (ph+1 < ktot){ swrite((ph+1)&1); gload(ph+2); } }
      MFMA_(accM[0][0], a0h, bh0); MFMA_(accX[0][0], a0h, bl0); MFMA_(accX[0][0], a0l, bh0);
      MFMA_(accM[1][0], a1h, bh0); MFMA_(accX[1][0], a1h, bl0); MFMA_(accX[1][0], a1l, bh0);
      MFMA_(accM[0][1], a0h, bh1); MFMA_(accX[0][1], a0h, bl1); MFMA_(accX[0][1], a0l, bh1);
      MFMA_(accM[1][1], a1h, bh1); MFMA_(accX[1][1], a1h, bl1); MFMA_(accX[1][1], a1l, bh1);
    }
    __syncthreads();
  }

  // ---- epilogue: two col-halves; z (128x128) -> LDS regroup -> LSTM cell
  const int cq = w >> 1;
  for (int hf=0; hf<2; ++hf){
    if ((cq>>1) == hf){
#pragma unroll
      for (int tm=0;tm<2;tm++)
#pragma unroll
       for (int tn=0;tn<2;tn++){
        int lcol = (cq&1)*64 + tn*32 + (lane&31);
        float bv = bias[ct8*256 + hf*128 + lcol];
#pragma unroll
        for (int r=0;r<16;r++){
          int lrow = (w&1)*64 + tm*32 + (r&3) + 8*(r>>2) + 4*(lane>>5);
          sm.z[lrow*128 + lcol] = accM[tm][tn][r] + 0.000244140625f*accX[tm][tn][r] + bv;
        }
       }
    }
    __syncthreads();
    const int nb = ct8*64 + hf*32;
#pragma unroll
    for (int it=0; it<8; ++it){
      int idx = it*512 + tid;
      int nq = idx & 31, row = idx >> 5;
      float4 g4 = *(const float4*)&sm.z[row*128 + nq*4];
      int m = mbase + row, n = nb + nq;
      float cp = p.first ? 0.f : cbuf[(size_t)m*512 + n];
      float cc = sigf(g4.y)*cp + sigf(g4.x)*tanhf(g4.z);
      float hv = sigf(g4.w)*tanhf(cc);
      cbuf[(size_t)m*512 + n] = cc;
      f16 hi = (f16)hv;
      f16 lo = (f16)((hv - (float)hi)*4096.0f);
      hhb[(size_t)m*p.ldh + n] = hi;
      hlb[(size_t)m*p.ldh + n] = lo;
      if (h2) h2[(size_t)m*p.ldh2 + n] = hv;
    }
    __syncthreads();
  }
}

// ------------------------------------------- prep: W in MFMA fragment order
// L0 K padded to 1088: [Wih 513 | pad 63 | Whh 512] -> x-part 576 = 9 BK64.
__global__ void prep_w0(const float* Wih, const float* Whh, const float* b0,
                        f16* Wfh, f16* Wfl, float* bp){
  int gid = blockIdx.x*blockDim.x + threadIdx.x;
  const int PER_DIR = 68*64*64*8;
  if (gid >= 2*PER_DIR) return;
  int dir = gid / PER_DIR;
  int rem = gid % PER_DIR;
  int j = rem & 7, lane = (rem>>3)&63, ct = (rem>>9)&63, kt16 = rem>>15;
  int n4g = ct*32 + (lane&31);
  int n = n4g>>2, g = n4g&3;
  int srow = dir*2048 + g*512 + n;
  int k = kt16*16 + ((lane>>5)<<3) + j;
  float v;
  if (k < 513)       v = Wih[(size_t)srow*513 + k];
  else if (k < 576)  v = 0.f;
  else               v = Whh[(size_t)srow*512 + (k-576)];
  f16 hi = (f16)v;
  Wfh[gid] = hi;
  Wfl[gid] = (f16)((v - (float)hi)*4096.0f);
  if (kt16==0 && (lane>>5)==0 && j==0) bp[dir*2048 + n4g] = b0[srow];
}

__global__ void prep_w1(const float* Wih, const float* Whh, const float* b1,
                        f16* Wfh, f16* Wfl, float* bp){
  int gid = blockIdx.x*blockDim.x + threadIdx.x;
  const int PER_DIR = 96*64*64*8;
  if (gid >= 2*PER_DIR) return;
  int dir = gid / PER_DIR;
  int rem = gid % PER_DIR;
  int j = rem & 7, lane = (rem>>3)&63, ct = (rem>>9)&63, kt16 = rem>>15;
  int n4g = ct*32 + (lane&31);
  int n = n4g>>2, g = n4g&3;
  int srow = dir*2048 + g*512 + n;
  int k = kt16*16 + ((lane>>5)<<3) + j;     // [Wih 1024 | Whh 512]
  float v;
  if (k < 1024) v = Wih[(size_t)srow*1024 + k];
  else          v = Whh[(size_t)srow*512 + (k-1024)];
  f16 hi = (f16)v;
  Wfh[gid] = hi;
  Wfl[gid] = (f16)((v - (float)hi)*4096.0f);
  if (kt16==0 && (lane>>5)==0 && j==0) bp[dir*2048 + n4g] = b1[srow];
}

__global__ void prep_emb(const float* emb, f16* eh, f16* el){
  int gid = blockIdx.x*blockDim.x + threadIdx.x;
  if (gid >= VOC_*256) return;
  float v = emb[gid];
  f16 hi = (f16)v;
  eh[gid] = hi;
  el[gid] = (f16)((v - (float)hi)*4096.0f);
}

__global__ void prep_mlpwt(const float* mW, float* wt){
  int gid = blockIdx.x*blockDim.x + threadIdx.x;
  if (gid >= 100*1040) return;
  int j = gid / 1040, k = gid % 1040;
  wt[k*100 + j] = mW[gid];
}

__global__ __launch_bounds__(128) void prep_encproj(const float* enc, const float* delv,
                        const float* holdv, const float* m1W, const float* m1b, float* ep){
  int r = blockIdx.x;
  __shared__ float row[256];
  const float* src = (r < VOC_) ? enc + (size_t)r*256 : (r == VOC_ ? delv : holdv);
  for (int i=threadIdx.x;i<256;i+=128) row[i]=src[i];
  __syncthreads();
  int j = threadIdx.x;
  if (j < 100){
    double s = (double)m1b[j];
    const float* wr = m1W + (size_t)j*298;
    for (int k=0;k<256;k++) s += (double)wr[k] * (double)row[k];
    ep[(size_t)r*100 + j] = (float)s;
  }
}

__global__ void init_st(const int* ids, const int* seqlen, int* st, int* len){
  int gid = blockIdx.x*blockDim.x + threadIdx.x;
  if (gid < B_*L_) st[gid] = ids[gid];
  if (gid < B_)    len[gid] = seqlen[gid];
}

__global__ void sentinel(float* out, float v){
  int gid = blockIdx.x*blockDim.x + threadIdx.x;
  if (gid < B_*NSTEP_) out[gid] = v;
}

// ------------------------------------------------- scoring + sequence edit
__global__ __launch_bounds__(128) void score_update(
    const float* pooled, const float* keypos, const float* mWt, const float* mb,
    const float* ep, const float* m1W, const int* repw, const int* valid,
    int* st, int* len, float* outPis, float* outActs, int step, int pos, int b0){
  int b = blockIdx.x;
  int bg = b0 + b;
  __shared__ float rep[1040];
  __shared__ float r100[100];
  __shared__ double sc[42];
  int tid = threadIdx.x;
  for (int i=tid;i<1024;i+=128) rep[i] = pooled[(size_t)b*1024+i];
  if (tid < 16){
    if (tid == 0) rep[1024] = keypos[bg*L_+pos];
    else          rep[1024+tid] = ((tid-1)==pos) ? 1.f : 0.f;
  }
  __syncthreads();
  if (tid < 100){
    double s = (double)mb[tid];
    for (int k=0;k<1040;k++) s += (double)mWt[k*100+tid] * (double)rep[k];
    r100[tid] = (float)s;
  }
  __syncthreads();
  if (tid < 42){
    int row = (tid < 40) ? repw[((size_t)bg*NSTEP_+step)*40 + tid] : (VOC_ + (tid-40));
    const float* er = ep + (size_t)row*100;
    double s = 0.0;
    for (int j=0;j<100;j++) s += (double)er[j] * (double)r100[j];
    for (int j=0;j<100;j++) s += (double)m1W[j*298 + 256 + tid] * (double)r100[j];
    sc[tid] = s;
  }
  __syncthreads();
  if (tid == 0){
    double mx = sc[0]; int am = 0;
    for (int k=1;k<42;k++) if (sc[k] > mx){ mx = sc[k]; am = k; }
    double sum = 0.0;
    for (int k=0;k<42;k++) sum += exp(sc[k]-mx);
    float pi = (float)(1.0/sum);
    int vid = valid[bg*NSTEP_+step];
    int ln  = len[bg];
    int repb = (am < 20) ? 1 : 0;
    int insb = (am >= 20 && am < 40) ? 1 : 0;
    int delb = (am == 40) ? 1 : 0;
    int repf = repb*vid;
    int insf = insb*vid*(((ln+insb) <= 15) ? 1 : 0);
    int delf = delb*vid*(((ln-delb) >  2) ? 1 : 0);
    int T = L_ - pos;
    int tail[13];
    for (int j=0;j<T;j++) tail[j] = st[bg*L_+pos+j];
    int aw = repw[((size_t)bg*NSTEP_+step)*40 + (am < 20 ? am : 19)];
    for (int j=0;j<T;j++){
      int rv = (j==0) ? aw : tail[j];
      int iv = (j==0) ? aw : tail[j-1];
      int dv = (j < T-1) ? tail[j+1] : PAD_;
      int hv = tail[j];
      int nv = repf ? rv : (insf ? iv : (delf ? dv : hv));
      st[bg*L_+pos+j] = nv;
    }
    len[bg] = ln + insf - delf;
    outPis[bg*NSTEP_+step]  = pi;
    outActs[bg*NSTEP_+step] = (float)am;
  }
}

__global__ void finalize(const int* st, const int* len, float* out){
  int gid = blockIdx.x*blockDim.x + threadIdx.x;
  if (gid < B_*L_)            out[2*B_*NSTEP_ + gid] = (float)st[gid];
  else if (gid < B_*L_ + B_)  out[2*B_*NSTEP_ + B_*L_ + (gid - B_*L_)] = (float)len[gid - B_*L_];
}

// ---------------------------------------------------------------- launch
extern "C" void kernel_launch(void* const* d_in, const int* in_sizes, int n_in,
                              void* d_out, int out_size, void* d_ws, size_t ws_size,
                              hipStream_t stream) {
  const int*   ids    = (const int*)  d_in[0];
  const float* keypos = (const float*)d_in[1];
  const int*   seqlen = (const int*)  d_in[2];
  const int*   repw   = (const int*)  d_in[3];
  const int*   valid  = (const int*)  d_in[4];
  const float* emb    = (const float*)d_in[5];
  const float* enc    = (const float*)d_in[6];
  const float* Wih0   = (const float*)d_in[7];
  const float* Whh0   = (const float*)d_in[8];
  const float* b0     = (const float*)d_in[9];
  const float* Wih1   = (const float*)d_in[10];
  const float* Whh1   = (const float*)d_in[11];
  const float* b1     = (const float*)d_in[12];
  const float* delv   = (const float*)d_in[13];
  const float* holdv  = (const float*)d_in[14];
  const float* mW     = (const float*)d_in[15];
  const float* mb     = (const float*)d_in[16];
  const float* m1W    = (const float*)d_in[17];
  const float* m1b    = (const float*)d_in[18];
  float* out = (float*)d_out;

  const size_t W0PD = (size_t)68*64*64*8;   // f16 per dir (K padded to 1088)
  const size_t W1PD = (size_t)96*64*64*8;

  char* ws = (char*)d_ws;
  size_t off = 0;
  auto allocB = [&](size_t bytes) -> char* {
    char* pp = ws + off; off += (bytes + 255) & ~size_t(255); return pp;
  };
  f16*  Wf0h = (f16*)allocB(2*W0PD*2);
  f16*  Wf0l = (f16*)allocB(2*W0PD*2);
  f16*  Wf1h = (f16*)allocB(2*W1PD*2);
  f16*  Wf1l = (f16*)allocB(2*W1PD*2);
  float* bp0 = (float*)allocB(4096*4);
  float* bp1 = (float*)allocB(4096*4);
  f16*  embH = (f16*)allocB((size_t)VOC_*256*2);
  f16*  embL = (f16*)allocB((size_t)VOC_*256*2);
  float* mWt = (float*)allocB(104000*4);
  float* ep  = (float*)allocB((size_t)30007*100*4);
  int* stbuf  = (int*)allocB(B_*L_*4);
  int* lenbuf = (int*)allocB(B_*4);
  size_t fixedB = off;

  const int cands[6] = {4096, 2048, 1024, 512, 256, 128};
  int Bc = 0;
  for (int ci=0; ci<6; ++ci){
    size_t c = cands[ci];
    size_t chunkB = c*(size_t)(15*1024*2*2 + 4*512*2*2 + 2*512*4 + 2*512*4 + 1024*4) + 8*256;
    if (fixedB + chunkB <= ws_size){ Bc = (int)c; break; }
  }
  if (!Bc){
    float code = 100000.0f + (float)(ws_size >> 20);
    sentinel<<<(B_*NSTEP_+255)/256,256,0,stream>>>(out, code);
    return;
  }
  f16* o0h = (f16*)allocB((size_t)L_*Bc*1024*2);
  f16* o0l = (f16*)allocB((size_t)L_*Bc*1024*2);
  f16* h1h = (f16*)allocB((size_t)4*Bc*512*2);
  f16* h1l = (f16*)allocB((size_t)4*Bc*512*2);
  float* c0 = (float*)allocB((size_t)2*Bc*512*4);
  float* c1 = (float*)allocB((size_t)2*Bc*512*4);
  float* pooled = (float*)allocB((size_t)Bc*1024*4);

  prep_w0<<<(int)((2*W0PD+255)/256),256,0,stream>>>(Wih0, Whh0, b0, Wf0h, Wf0l, bp0);
  prep_w1<<<(int)((2*W1PD+255)/256),256,0,stream>>>(Wih1, Whh1, b1, Wf1h, Wf1l, bp1);
  prep_emb<<<(VOC_*256+255)/256,256,0,stream>>>(emb, embH, embL);
  prep_mlpwt<<<(100*1040+255)/256,256,0,stream>>>(mW, mWt);
  prep_encproj<<<30007,128,0,stream>>>(enc, delv, holdv, m1W, m1b, ep);
  init_st<<<(B_*L_+255)/256,256,0,stream>>>(ids, seqlen, stbuf, lenbuf);

  for (int b0c=0; b0c<B_; b0c+=Bc){
    for (int step=0; step<NSTEP_; ++step){
      int pos = step + 2;   // i % 12 + 2 for i=0..4

      // ---- layer 0: full 15 timesteps, fw (t=ts) + bw (t=14-ts)
      for (int ts=0; ts<L_; ++ts){
        int tf = ts, tb = 14-ts;
        RecParams p{};
        p.gather = 1; p.t_0 = tf; p.t_1 = tb; p.pos = pos; p.b0c = b0c;
        p.embH = embH; p.embL = embL; p.st = stbuf; p.ids = ids;
        p.k1p = 9; p.k2p = ts ? 8 : 0;
        size_t of0 = (size_t)(ts?tf-1:0)*Bc*1024;
        size_t of1 = (size_t)(ts?tb+1:0)*Bc*1024 + (ts?512:0);
        p.A2h_0 = o0h + of0;  p.A2l_0 = o0l + of0;
        p.A2h_1 = o0h + of1;  p.A2l_1 = o0l + of1;
        p.lda2 = 1024;
        p.Wfh_0 = Wf0h;        p.Wfl_0 = Wf0l;
        p.Wfh_1 = Wf0h + W0PD; p.Wfl_1 = Wf0l + W0PD;
        p.bias_0 = bp0; p.bias_1 = bp0 + 2048;
        p.c_0 = c0; p.c_1 = c0 + (size_t)Bc*512;
        p.hh_0 = o0h + (size_t)tf*Bc*1024;       p.hl_0 = o0l + (size_t)tf*Bc*1024;
        p.hh_1 = o0h + (size_t)tb*Bc*1024 + 512; p.hl_1 = o0l + (size_t)tb*Bc*1024 + 512;
        p.ldh = 1024;
        p.h2_0 = nullptr; p.h2_1 = nullptr; p.ldh2 = 1024;
        p.first = (ts==0); p.act0 = 1; p.act1 = 1;
        rec_gemm<<<dim3(16,Bc/128),512,0,stream>>>(p);
      }

      // ---- layer 1: fw needs t<=pos only, bw needs t>=pos only
      int nL1 = L_ - pos;
      for (int ts=0; ts<nL1; ++ts){
        RecParams p{};
        int tf = ts, tb = 14-ts;
        int parR = (ts-1)&1, parW = ts&1;
        p.gather = 0;
        p.A1h_0 = o0h + (size_t)tf*Bc*1024;  p.A1l_0 = o0l + (size_t)tf*Bc*1024;
        p.A1h_1 = o0h + (size_t)tb*Bc*1024;  p.A1l_1 = o0l + (size_t)tb*Bc*1024;
        p.lda1 = 1024; p.k1p = 16;
        p.k2p  = ts ? 8 : 0;
        size_t r0 = (size_t)(0*2 + (ts?parR:0))*Bc*512;
        size_t r1 = (size_t)(1*2 + (ts?parR:0))*Bc*512;
        p.A2h_0 = h1h + r0; p.A2l_0 = h1l + r0;
        p.A2h_1 = h1h + r1; p.A2l_1 = h1l + r1;
        p.lda2 = 512;
        p.Wfh_0 = Wf1h;        p.Wfl_0 = Wf1l;
        p.Wfh_1 = Wf1h + W1PD; p.Wfl_1 = Wf1l + W1PD;
        p.bias_0 = bp1; p.bias_1 = bp1 + 2048;
        p.c_0 = c1; p.c_1 = c1 + (size_t)Bc*512;
        size_t w0 = (size_t)(0*2 + parW)*Bc*512;
        size_t w1 = (size_t)(1*2 + parW)*Bc*512;
        p.hh_0 = h1h + w0; p.hl_0 = h1l + w0;
        p.hh_1 = h1h + w1; p.hl_1 = h1l + w1;
        p.ldh = 512;
        p.h2_0 = (ts == pos)    ? pooled        : nullptr;
        p.h2_1 = (ts == 14-pos) ? (pooled+512)  : nullptr;
        p.ldh2 = 1024;
        p.first = (ts==0);
        p.act0 = (ts <= pos) ? 1 : 0; p.act1 = 1;
        rec_gemm<<<dim3(16,Bc/128),512,0,stream>>>(p);
      }

      score_update<<<Bc,128,0,stream>>>(pooled, keypos, mWt, mb, ep, m1W, repw, valid,
                                        stbuf, lenbuf, out, out + B_*NSTEP_, step, pos, b0c);
    }
  }
  finalize<<<(B_*L_+B_+255)/256,256,0,stream>>>(stbuf, lenbuf, out);
}